// Round 5
// baseline (1733.968 us; speedup 1.0000x reference)
//
#include <hip/hip_runtime.h>
#include <math.h>

// ---------------- problem constants ----------------
#define NUM_CLASSES 80
#define TOPK 300
#define NTOT 10647             // 3*(169+676+2704)
#define L0END 507
#define L1END 2535
#define NPADMAX 16384
#define NMS_T 384

// level 0: 13x13 (mask 6,7,8), level 1: 26x26 (mask 3,4,5), level 2: 52x52 (mask 0,1,2)
__constant__ float ANCWf[3][3] = {{116.f,156.f,373.f},{30.f,62.f,59.f},{10.f,16.f,33.f}};
__constant__ float ANCHf[3][3] = {{90.f,198.f,326.f},{61.f,45.f,119.f},{13.f,30.f,23.f}};

// correctly-rounded f32 exp (f64 exp, rounded once) — matches numpy f32 exp
__device__ __forceinline__ float expcr(float x) { return (float)exp((double)x); }
// numpy-style f32 sigmoid: op-by-op 1/(1+exp(-x)), each op f32 correctly rounded
__device__ __forceinline__ float sigf(float x) {
    float e = expcr(-x);
    return __fdiv_rn(1.0f, __fadd_rn(1.0f, e));
}

// locate anchor idx -> level geometry + channel-0 pointer (stride hw between channels)
__device__ __forceinline__ const float* locate(const float* f0, const float* f1, const float* f2,
                                               int img, int idx,
                                               int& level, int& hw, int& W, int& hrow, int& wcol, int& a) {
    int local, cell;
    const float* base;
    if (idx < L0END) {
        level = 0; local = idx; hw = 169; W = 13;
        base = f0 + (size_t)img * 43095;        // 255*169
    } else if (idx < L1END) {
        level = 1; local = idx - L0END; hw = 676; W = 26;
        base = f1 + (size_t)img * 172380;       // 255*676
    } else {
        level = 2; local = idx - L1END; hw = 2704; W = 52;
        base = f2 + (size_t)img * 689520;       // 255*2704
    }
    a = local / hw; cell = local - a * hw;
    hrow = cell / W; wcol = cell - hrow * W;
    return base + (size_t)(a * 85) * hw + cell;
}

// ---------------- kernel 1: numpy-f32 score + compaction ----------------
// Only entries with score >= 0.5 can occupy nonzero output rows; sub-threshold
// entries rank after all positive ones and can only suppress other zero rows.
__global__ void score_kernel(const float* __restrict__ f0, const float* __restrict__ f1,
                             const float* __restrict__ f2,
                             unsigned int* __restrict__ counters,
                             unsigned long long* __restrict__ keys, int total) {
    int t = blockIdx.x * blockDim.x + threadIdx.x;
    if (t >= total) return;
    int img = t / NTOT;
    int idx = t - img * NTOT;
    int level, hw, W, hrow, wcol, a;
    const float* p = locate(f0, f1, f2, img, idx, level, hw, W, hrow, wcol, a);

    float obj = sigf(p[4 * hw]);
    // max over class logits; CR-f32 sigmoid is monotone nondecreasing, so
    // max_c sigf(v_c) == sigf(max_c v_c) bit-exactly (value, not index).
    float mx = p[5 * hw];
    for (int c = 1; c < NUM_CLASSES; ++c) {
        float v = p[(5 + c) * hw];
        if (v > mx) mx = v;
    }
    float cls = sigf(mx);
    float s = __fmul_rn(obj, cls);
    if (s >= 0.5f) {
        unsigned slot = atomicAdd(&counters[img], 1u);
        keys[(size_t)img * NTOT + slot] =
            ((unsigned long long)__float_as_uint(s) << 32) | (unsigned int)(~(unsigned int)idx);
    }
}

// ---------------- kernel 2: per-image top-300 via bitonic sort of next-pow2(n) ----------------
// Full key = (score_bits, ~idx): sort is deterministic regardless of atomic
// insertion order, and ties break exactly like lax.top_k (score desc, idx asc).
__global__ __launch_bounds__(1024) void topk_kernel(const unsigned int* __restrict__ counters,
                                                    const unsigned long long* __restrict__ keys,
                                                    unsigned int* __restrict__ top_idx) {
    __shared__ unsigned long long s[NPADMAX];   // 128 KiB
    int img = blockIdx.x;
    int tid = threadIdx.x;
    int n = (int)counters[img];
    if (n > NTOT) n = NTOT;
    int NP = 512;
    while (NP < n) NP <<= 1;
    const unsigned long long* k = keys + (size_t)img * NTOT;
    for (int i = tid; i < NP; i += 1024) s[i] = (i < n) ? k[i] : 0ULL;
    __syncthreads();
    for (int kk = 2; kk <= NP; kk <<= 1) {
        for (int j = kk >> 1; j > 0; j >>= 1) {
            for (int t = tid; t < NP; t += 1024) {
                int l = t ^ j;
                if (l > t) {
                    bool desc = ((t & kk) == 0);
                    unsigned long long av = s[t], bv = s[l];
                    if ((av < bv) == desc) { s[t] = bv; s[l] = av; }
                }
            }
            __syncthreads();
        }
    }
    for (int i = tid; i < TOPK; i += 1024) {
        top_idx[img * TOPK + i] = ~((unsigned int)s[i]);   // zero key -> 0xFFFFFFFF sentinel
    }
}

// ---------------- kernel 3: NMS via suppression bit-matrix (2 barriers) ----------------
__global__ __launch_bounds__(NMS_T) void nms_kernel(const float* __restrict__ f0, const float* __restrict__ f1,
                                                    const float* __restrict__ f2,
                                                    const unsigned int* __restrict__ top_idx,
                                                    float* __restrict__ out) {
    __shared__ float bx0[TOPK], bx1[TOPK], bx2[TOPK], bx3[TOPK];
    __shared__ float bb0[TOPK], bb1[TOPK], bb2[TOPK], bb3[TOPK];
    __shared__ float area[TOPK], sc[TOPK], clsf[TOPK];
    __shared__ unsigned long long sup[TOPK][5];
    __shared__ unsigned long long keepm[5];

    int img = blockIdx.x;
    int tid = threadIdx.x;

    if (tid < TOPK) {
        unsigned int idx = top_idx[img * TOPK + tid];
        if (idx == 0xFFFFFFFFu) {
            // missing row: exact zeros; (0,0,0,0) box has zero IoU vs anything
            bx0[tid] = 0.f; bx1[tid] = 0.f; bx2[tid] = 0.f; bx3[tid] = 0.f;
            bb0[tid] = 0.f; bb1[tid] = 0.f; bb2[tid] = 0.f; bb3[tid] = 0.f;
            area[tid] = 0.f; sc[tid] = 0.f; clsf[tid] = 0.f;
        } else {
            int level, hw, W, hrow, wcol, a;
            const float* p = locate(f0, f1, f2, img, (int)idx, level, hw, W, hrow, wcol, a);

            float x = __fdiv_rn(__fadd_rn(sigf(p[0]),  (float)wcol), (float)W);
            float y = __fdiv_rn(__fadd_rn(sigf(p[hw]), (float)hrow), (float)W);   // H == W per level
            float wd = __fdiv_rn(__fmul_rn(expcr(p[2 * hw]), ANCWf[level][a]), 416.0f);
            float ht = __fdiv_rn(__fmul_rn(expcr(p[3 * hw]), ANCHf[level][a]), 416.0f);
            float obj = sigf(p[4 * hw]);

            // literal reference: argmax over per-class f32 sigmoids (first max wins)
            float mxs = sigf(p[5 * hw]);
            int cid = 0;
            for (int c = 1; c < NUM_CLASSES; ++c) {
                float v = sigf(p[(5 + c) * hw]);
                if (v > mxs) { mxs = v; cid = c; }
            }
            float score = __fmul_rn(obj, mxs);
            if (!(score >= 0.5f)) score = 0.0f;   // can't happen for compacted rows, kept for fidelity

            float hx = __fmul_rn(wd, 0.5f);
            float hy = __fmul_rn(ht, 0.5f);
            float x1 = __fmul_rn(__fsub_rn(x, hx), 416.0f);
            float y1 = __fmul_rn(__fsub_rn(y, hy), 416.0f);
            float x2 = __fmul_rn(__fadd_rn(x, hx), 416.0f);
            float y2 = __fmul_rn(__fadd_rn(y, hy), 416.0f);
            float off = __fmul_rn((float)cid, 832.0f);   // 2*INPUT

            bx0[tid] = x1; bx1[tid] = y1; bx2[tid] = x2; bx3[tid] = y2;
            float b0 = __fadd_rn(x1, off), b1 = __fadd_rn(y1, off);
            float b2 = __fadd_rn(x2, off), b3 = __fadd_rn(y2, off);
            bb0[tid] = b0; bb1[tid] = b1; bb2[tid] = b2; bb3[tid] = b3;
            area[tid] = __fmul_rn(__fsub_rn(b2, b0), __fsub_rn(b3, b1));
            sc[tid] = score;
            clsf[tid] = (float)cid;
        }
    }
    __syncthreads();

    // suppression bit-matrix: sup[r] bit j set iff j > r and IoU(r,j) > 0.3
    for (int r = tid; r < TOPK; r += NMS_T) {
        float a0 = bb0[r], a1 = bb1[r], a2 = bb2[r], a3 = bb3[r], aa = area[r];
        for (int w = 0; w < 5; ++w) {
            unsigned long long m = 0ULL;
            int jbase = w * 64;
            int jend = (jbase + 64 < TOPK) ? 64 : (TOPK - jbase);
            for (int jj = 0; jj < jend; ++jj) {
                int j = jbase + jj;
                if (j <= r) continue;
                float ltx = fmaxf(a0, bb0[j]);
                float lty = fmaxf(a1, bb1[j]);
                float rbx = fminf(a2, bb2[j]);
                float rby = fminf(a3, bb3[j]);
                float wx = fmaxf(__fsub_rn(rbx, ltx), 0.0f);
                float wy = fmaxf(__fsub_rn(rby, lty), 0.0f);
                float inter = __fmul_rn(wx, wy);
                float denom = __fadd_rn(__fsub_rn(__fadd_rn(aa, area[j]), inter), 1e-6f);
                float iou = __fdiv_rn(inter, denom);
                if (iou > 0.3f) m |= (1ULL << jj);
            }
            sup[r][w] = m;
        }
    }
    __syncthreads();

    // serial greedy scan over the bit-matrix (exact reference order)
    if (tid == 0) {
        unsigned long long kp0 = ~0ULL, kp1 = ~0ULL, kp2 = ~0ULL, kp3 = ~0ULL, kp4 = ~0ULL;
        for (int i = 0; i < TOPK; ++i) {
            unsigned long long kw;
            switch (i >> 6) {
                case 0: kw = kp0; break; case 1: kw = kp1; break; case 2: kw = kp2; break;
                case 3: kw = kp3; break; default: kw = kp4; break;
            }
            if ((kw >> (i & 63)) & 1ULL) {
                kp0 &= ~sup[i][0]; kp1 &= ~sup[i][1]; kp2 &= ~sup[i][2];
                kp3 &= ~sup[i][3]; kp4 &= ~sup[i][4];
            }
        }
        keepm[0] = kp0; keepm[1] = kp1; keepm[2] = kp2; keepm[3] = kp3; keepm[4] = kp4;
    }
    __syncthreads();

    if (tid < TOPK) {
        bool kept = (keepm[tid >> 6] >> (tid & 63)) & 1ULL;
        float m = (kept && (sc[tid] > 0.0f)) ? 1.0f : 0.0f;
        float* o = out + ((size_t)img * TOPK + tid) * 6;
        o[0] = __fmul_rn(bx0[tid], m);
        o[1] = __fmul_rn(bx1[tid], m);
        o[2] = __fmul_rn(bx2[tid], m);
        o[3] = __fmul_rn(bx3[tid], m);
        o[4] = __fmul_rn(sc[tid], m);
        o[5] = __fmul_rn(clsf[tid], m);
    }
}

extern "C" void kernel_launch(void* const* d_in, const int* in_sizes, int n_in,
                              void* d_out, int out_size, void* d_ws, size_t ws_size,
                              hipStream_t stream) {
    const float* f0 = (const float*)d_in[0];
    const float* f1 = (const float*)d_in[1];
    const float* f2 = (const float*)d_in[2];
    float* out = (float*)d_out;

    int B = in_sizes[0] / 43095;   // 255*13*13
    int total = B * NTOT;

    // workspace layout: [counters B u32][pad][top_idx B*300 u32][pad][keys B*NTOT u64]
    unsigned int* counters = (unsigned int*)d_ws;
    unsigned int* top_idx = (unsigned int*)((char*)d_ws + 1024);
    size_t keys_off = 1024 + ((size_t)B * TOPK * sizeof(unsigned int) + 1023) / 1024 * 1024;
    unsigned long long* keys = (unsigned long long*)((char*)d_ws + keys_off);

    hipMemsetAsync(counters, 0, (size_t)B * sizeof(unsigned int), stream);
    score_kernel<<<(total + 255) / 256, 256, 0, stream>>>(f0, f1, f2, counters, keys, total);
    topk_kernel<<<B, 1024, 0, stream>>>(counters, keys, top_idx);
    nms_kernel<<<B, NMS_T, 0, stream>>>(f0, f1, f2, top_idx, out);
}

// Round 6
// 271.200 us; speedup vs baseline: 6.3937x; 6.3937x over previous
//
#include <hip/hip_runtime.h>
#include <math.h>

// ---------------- problem constants ----------------
#define NUM_CLASSES 80
#define TOPK 300
#define NTOT 10647             // 3*(169+676+2704)
#define L0END 507
#define L1END 2535
#define NPADMAX 16384
#define NMS_T 384
#define CTR_STRIDE 64          // one counter per 256B

// level 0: 13x13 (mask 6,7,8), level 1: 26x26 (mask 3,4,5), level 2: 52x52 (mask 0,1,2)
__constant__ float ANCWf[3][3] = {{116.f,156.f,373.f},{30.f,62.f,59.f},{10.f,16.f,33.f}};
__constant__ float ANCHf[3][3] = {{90.f,198.f,326.f},{61.f,45.f,119.f},{13.f,30.f,23.f}};

// correctly-rounded f32 exp (f64 exp, rounded once) — matches numpy f32 exp
__device__ __forceinline__ float expcr(float x) { return (float)exp((double)x); }
// numpy-style f32 sigmoid: op-by-op 1/(1+exp(-x)), each op f32 correctly rounded
__device__ __forceinline__ float sigf(float x) {
    float e = expcr(-x);
    return __fdiv_rn(1.0f, __fadd_rn(1.0f, e));
}

// locate anchor idx -> level geometry + channel-0 pointer (stride hw between channels)
__device__ __forceinline__ const float* locate(const float* f0, const float* f1, const float* f2,
                                               int img, int idx,
                                               int& level, int& hw, int& W, int& hrow, int& wcol, int& a) {
    int local, cell;
    const float* base;
    if (idx < L0END) {
        level = 0; local = idx; hw = 169; W = 13;
        base = f0 + (size_t)img * 43095;        // 255*169
    } else if (idx < L1END) {
        level = 1; local = idx - L0END; hw = 676; W = 26;
        base = f1 + (size_t)img * 172380;       // 255*676
    } else {
        level = 2; local = idx - L1END; hw = 2704; W = 52;
        base = f2 + (size_t)img * 689520;       // 255*2704
    }
    a = local / hw; cell = local - a * hw;
    hrow = cell / W; wcol = cell - hrow * W;
    return base + (size_t)(a * 85) * hw + cell;
}

// ---------------- kernel 1: numpy-f32 score + wave-aggregated compaction ----------------
// Thread ranges (wave-aligned per image so a wave never spans two images):
//   [0,           32*512)  : level 0 scalar, img=t>>9,  r=t&511,  valid r<507
//   [32*512,      64*512)  : level 1 float4, img=t>>9,  r=t&511,  valid r<507 (r=a*169+grp)
//   [64*512, 64*512+32*2048): level 2 float4, img=t>>11, r=t&2047, valid r<2028 (r=a*676+grp)
__global__ void score_kernel(const float* __restrict__ f0, const float* __restrict__ f1,
                             const float* __restrict__ f2,
                             unsigned int* __restrict__ counters,
                             unsigned long long* __restrict__ keys) {
    int t = blockIdx.x * blockDim.x + threadIdx.x;
    int lane = threadIdx.x & 63;

    bool pred[4] = {false, false, false, false};
    unsigned int kidx[4];
    float kscore[4];
    int img;

    if (t < 32 * 512) {
        // ---- level 0, scalar ----
        img = t >> 9;
        int r = t & 511;
        if (r < 507) {
            int a = r / 169, cell = r - a * 169;
            const float* p = f0 + (size_t)img * 43095 + (size_t)(a * 85) * 169 + cell;
            float obj = sigf(p[4 * 169]);
            float mx = p[5 * 169];
            #pragma unroll 8
            for (int c = 1; c < NUM_CLASSES; ++c) {
                float v = p[(5 + c) * 169];
                if (v > mx) mx = v;
            }
            float s = __fmul_rn(obj, sigf(mx));
            if (s >= 0.5f) { pred[0] = true; kidx[0] = r; kscore[0] = s; }
        }
    } else if (t < 64 * 512) {
        // ---- level 1, float4 (hw=676, all strides %4==0 -> 16B aligned) ----
        int tt = t - 32 * 512;
        img = tt >> 9;
        int r = tt & 511;
        if (r < 507) {
            int a = r / 169, grp = r - a * 169;
            int cell0 = grp * 4;
            const float* p0 = f1 + (size_t)img * 172380 + (size_t)(a * 85) * 676 + cell0;
            float4 o4 = *(const float4*)(p0 + 4 * 676);
            float4 mx = *(const float4*)(p0 + 5 * 676);
            #pragma unroll 8
            for (int c = 1; c < NUM_CLASSES; ++c) {
                float4 v = *(const float4*)(p0 + (5 + c) * 676);
                mx.x = fmaxf(mx.x, v.x); mx.y = fmaxf(mx.y, v.y);
                mx.z = fmaxf(mx.z, v.z); mx.w = fmaxf(mx.w, v.w);
            }
            float ob[4] = {o4.x, o4.y, o4.z, o4.w};
            float mv[4] = {mx.x, mx.y, mx.z, mx.w};
            #pragma unroll
            for (int j = 0; j < 4; ++j) {
                float s = __fmul_rn(sigf(ob[j]), sigf(mv[j]));
                if (s >= 0.5f) { pred[j] = true; kidx[j] = L0END + a * 676 + cell0 + j; kscore[j] = s; }
            }
        }
    } else {
        // ---- level 2, float4 (hw=2704) ----
        int tt = t - 64 * 512;
        img = tt >> 11;
        int r = tt & 2047;
        if (r < 2028) {
            int a = r / 676, grp = r - a * 676;
            int cell0 = grp * 4;
            const float* p0 = f2 + (size_t)img * 689520 + (size_t)(a * 85) * 2704 + cell0;
            float4 o4 = *(const float4*)(p0 + 4 * 2704);
            float4 mx = *(const float4*)(p0 + 5 * 2704);
            #pragma unroll 8
            for (int c = 1; c < NUM_CLASSES; ++c) {
                float4 v = *(const float4*)(p0 + (5 + c) * 2704);
                mx.x = fmaxf(mx.x, v.x); mx.y = fmaxf(mx.y, v.y);
                mx.z = fmaxf(mx.z, v.z); mx.w = fmaxf(mx.w, v.w);
            }
            float ob[4] = {o4.x, o4.y, o4.z, o4.w};
            float mv[4] = {mx.x, mx.y, mx.z, mx.w};
            #pragma unroll
            for (int j = 0; j < 4; ++j) {
                float s = __fmul_rn(sigf(ob[j]), sigf(mv[j]));
                if (s >= 0.5f) { pred[j] = true; kidx[j] = L1END + a * 2704 + cell0 + j; kscore[j] = s; }
            }
        }
    }

    // wave-aggregated compaction: all lanes of a wave share one image.
    unsigned long long* kout = keys + (size_t)img * NTOT;
    unsigned int* ctr = &counters[img * CTR_STRIDE];
    #pragma unroll
    for (int j = 0; j < 4; ++j) {
        unsigned long long mask = __ballot(pred[j]);
        if (mask) {
            int lead = __ffsll((long long)mask) - 1;
            unsigned int base = 0;
            if (lane == lead) base = atomicAdd(ctr, (unsigned int)__popcll(mask));
            base = __shfl(base, lead, 64);
            if (pred[j]) {
                unsigned int pos = (unsigned int)__popcll(mask & ((1ULL << lane) - 1ULL));
                kout[base + pos] = ((unsigned long long)__float_as_uint(kscore[j]) << 32)
                                   | (unsigned int)(~kidx[j]);
            }
        }
    }
}

// ---------------- kernel 2: per-image top-300 via bitonic sort of next-pow2(n) ----------------
// Full key = (score_bits, ~idx): deterministic regardless of atomic insertion
// order; ties break exactly like lax.top_k (score desc, idx asc).
__global__ __launch_bounds__(1024) void topk_kernel(const unsigned int* __restrict__ counters,
                                                    const unsigned long long* __restrict__ keys,
                                                    unsigned int* __restrict__ top_idx) {
    __shared__ unsigned long long s[NPADMAX];   // 128 KiB
    int img = blockIdx.x;
    int tid = threadIdx.x;
    int n = (int)counters[img * CTR_STRIDE];
    if (n > NTOT) n = NTOT;
    int NP = 512;
    while (NP < n) NP <<= 1;
    const unsigned long long* k = keys + (size_t)img * NTOT;
    for (int i = tid; i < NP; i += 1024) s[i] = (i < n) ? k[i] : 0ULL;
    __syncthreads();
    for (int kk = 2; kk <= NP; kk <<= 1) {
        for (int j = kk >> 1; j > 0; j >>= 1) {
            for (int t = tid; t < NP; t += 1024) {
                int l = t ^ j;
                if (l > t) {
                    bool desc = ((t & kk) == 0);
                    unsigned long long av = s[t], bv = s[l];
                    if ((av < bv) == desc) { s[t] = bv; s[l] = av; }
                }
            }
            __syncthreads();
        }
    }
    for (int i = tid; i < TOPK; i += 1024) {
        top_idx[img * TOPK + i] = ~((unsigned int)s[i]);   // zero key -> 0xFFFFFFFF sentinel
    }
}

// ---------------- kernel 3: NMS via suppression bit-matrix (2 barriers) ----------------
__global__ __launch_bounds__(NMS_T) void nms_kernel(const float* __restrict__ f0, const float* __restrict__ f1,
                                                    const float* __restrict__ f2,
                                                    const unsigned int* __restrict__ top_idx,
                                                    float* __restrict__ out) {
    __shared__ float bx0[TOPK], bx1[TOPK], bx2[TOPK], bx3[TOPK];
    __shared__ float bb0[TOPK], bb1[TOPK], bb2[TOPK], bb3[TOPK];
    __shared__ float area[TOPK], sc[TOPK], clsf[TOPK];
    __shared__ unsigned long long sup[TOPK][5];
    __shared__ unsigned long long keepm[5];

    int img = blockIdx.x;
    int tid = threadIdx.x;

    if (tid < TOPK) {
        unsigned int idx = top_idx[img * TOPK + tid];
        if (idx == 0xFFFFFFFFu) {
            bx0[tid] = 0.f; bx1[tid] = 0.f; bx2[tid] = 0.f; bx3[tid] = 0.f;
            bb0[tid] = 0.f; bb1[tid] = 0.f; bb2[tid] = 0.f; bb3[tid] = 0.f;
            area[tid] = 0.f; sc[tid] = 0.f; clsf[tid] = 0.f;
        } else {
            int level, hw, W, hrow, wcol, a;
            const float* p = locate(f0, f1, f2, img, (int)idx, level, hw, W, hrow, wcol, a);

            float x = __fdiv_rn(__fadd_rn(sigf(p[0]),  (float)wcol), (float)W);
            float y = __fdiv_rn(__fadd_rn(sigf(p[hw]), (float)hrow), (float)W);   // H == W per level
            float wd = __fdiv_rn(__fmul_rn(expcr(p[2 * hw]), ANCWf[level][a]), 416.0f);
            float ht = __fdiv_rn(__fmul_rn(expcr(p[3 * hw]), ANCHf[level][a]), 416.0f);
            float obj = sigf(p[4 * hw]);

            // literal reference: argmax over per-class f32 sigmoids (first max wins)
            float mxs = sigf(p[5 * hw]);
            int cid = 0;
            for (int c = 1; c < NUM_CLASSES; ++c) {
                float v = sigf(p[(5 + c) * hw]);
                if (v > mxs) { mxs = v; cid = c; }
            }
            float score = __fmul_rn(obj, mxs);
            if (!(score >= 0.5f)) score = 0.0f;

            float hx = __fmul_rn(wd, 0.5f);
            float hy = __fmul_rn(ht, 0.5f);
            float x1 = __fmul_rn(__fsub_rn(x, hx), 416.0f);
            float y1 = __fmul_rn(__fsub_rn(y, hy), 416.0f);
            float x2 = __fmul_rn(__fadd_rn(x, hx), 416.0f);
            float y2 = __fmul_rn(__fadd_rn(y, hy), 416.0f);
            float off = __fmul_rn((float)cid, 832.0f);   // 2*INPUT

            bx0[tid] = x1; bx1[tid] = y1; bx2[tid] = x2; bx3[tid] = y2;
            float b0 = __fadd_rn(x1, off), b1 = __fadd_rn(y1, off);
            float b2 = __fadd_rn(x2, off), b3 = __fadd_rn(y2, off);
            bb0[tid] = b0; bb1[tid] = b1; bb2[tid] = b2; bb3[tid] = b3;
            area[tid] = __fmul_rn(__fsub_rn(b2, b0), __fsub_rn(b3, b1));
            sc[tid] = score;
            clsf[tid] = (float)cid;
        }
    }
    __syncthreads();

    // suppression bit-matrix: sup[r] bit j set iff j > r and IoU(r,j) > 0.3
    for (int r = tid; r < TOPK; r += NMS_T) {
        float a0 = bb0[r], a1 = bb1[r], a2 = bb2[r], a3 = bb3[r], aa = area[r];
        for (int w = 0; w < 5; ++w) {
            unsigned long long m = 0ULL;
            int jbase = w * 64;
            int jend = (jbase + 64 < TOPK) ? 64 : (TOPK - jbase);
            for (int jj = 0; jj < jend; ++jj) {
                int j = jbase + jj;
                if (j <= r) continue;
                float ltx = fmaxf(a0, bb0[j]);
                float lty = fmaxf(a1, bb1[j]);
                float rbx = fminf(a2, bb2[j]);
                float rby = fminf(a3, bb3[j]);
                float wx = fmaxf(__fsub_rn(rbx, ltx), 0.0f);
                float wy = fmaxf(__fsub_rn(rby, lty), 0.0f);
                float inter = __fmul_rn(wx, wy);
                float denom = __fadd_rn(__fsub_rn(__fadd_rn(aa, area[j]), inter), 1e-6f);
                float iou = __fdiv_rn(inter, denom);
                if (iou > 0.3f) m |= (1ULL << jj);
            }
            sup[r][w] = m;
        }
    }
    __syncthreads();

    // serial greedy scan over the bit-matrix (exact reference order)
    if (tid == 0) {
        unsigned long long kp0 = ~0ULL, kp1 = ~0ULL, kp2 = ~0ULL, kp3 = ~0ULL, kp4 = ~0ULL;
        for (int i = 0; i < TOPK; ++i) {
            unsigned long long kw;
            switch (i >> 6) {
                case 0: kw = kp0; break; case 1: kw = kp1; break; case 2: kw = kp2; break;
                case 3: kw = kp3; break; default: kw = kp4; break;
            }
            if ((kw >> (i & 63)) & 1ULL) {
                kp0 &= ~sup[i][0]; kp1 &= ~sup[i][1]; kp2 &= ~sup[i][2];
                kp3 &= ~sup[i][3]; kp4 &= ~sup[i][4];
            }
        }
        keepm[0] = kp0; keepm[1] = kp1; keepm[2] = kp2; keepm[3] = kp3; keepm[4] = kp4;
    }
    __syncthreads();

    if (tid < TOPK) {
        bool kept = (keepm[tid >> 6] >> (tid & 63)) & 1ULL;
        float m = (kept && (sc[tid] > 0.0f)) ? 1.0f : 0.0f;
        float* o = out + ((size_t)img * TOPK + tid) * 6;
        o[0] = __fmul_rn(bx0[tid], m);
        o[1] = __fmul_rn(bx1[tid], m);
        o[2] = __fmul_rn(bx2[tid], m);
        o[3] = __fmul_rn(bx3[tid], m);
        o[4] = __fmul_rn(sc[tid], m);
        o[5] = __fmul_rn(clsf[tid], m);
    }
}

extern "C" void kernel_launch(void* const* d_in, const int* in_sizes, int n_in,
                              void* d_out, int out_size, void* d_ws, size_t ws_size,
                              hipStream_t stream) {
    const float* f0 = (const float*)d_in[0];
    const float* f1 = (const float*)d_in[1];
    const float* f2 = (const float*)d_in[2];
    float* out = (float*)d_out;

    int B = in_sizes[0] / 43095;   // 255*13*13 (== 32 for this problem)

    // workspace: [counters B*64 u32 (padded)][top_idx B*300 u32][keys B*NTOT u64]
    unsigned int* counters = (unsigned int*)d_ws;
    size_t ctr_bytes = (size_t)B * CTR_STRIDE * sizeof(unsigned int);
    unsigned int* top_idx = (unsigned int*)((char*)d_ws + ctr_bytes);
    size_t keys_off = ctr_bytes + ((size_t)B * TOPK * sizeof(unsigned int) + 1023) / 1024 * 1024;
    unsigned long long* keys = (unsigned long long*)((char*)d_ws + keys_off);

    hipMemsetAsync(counters, 0, ctr_bytes, stream);
    // threads: 32*512 (L0) + 32*512 (L1) + 32*2048 (L2) = 98304
    score_kernel<<<98304 / 256, 256, 0, stream>>>(f0, f1, f2, counters, keys);
    topk_kernel<<<B, 1024, 0, stream>>>(counters, keys, top_idx);
    nms_kernel<<<B, NMS_T, 0, stream>>>(f0, f1, f2, top_idx, out);
}

// Round 7
// 253.203 us; speedup vs baseline: 6.8481x; 1.0711x over previous
//
#include <hip/hip_runtime.h>
#include <math.h>

// ---------------- problem constants ----------------
#define NUM_CLASSES 80
#define TOPK 300
#define NTOT 10647             // 3*(169+676+2704)
#define L0END 507
#define L1END 2535
#define NPADMAX 16384
#define NMS_T 384
#define CTR_STRIDE 64          // one counter per 256B

// level 0: 13x13 (mask 6,7,8), level 1: 26x26 (mask 3,4,5), level 2: 52x52 (mask 0,1,2)
__constant__ float ANCWf[3][3] = {{116.f,156.f,373.f},{30.f,62.f,59.f},{10.f,16.f,33.f}};
__constant__ float ANCHf[3][3] = {{90.f,198.f,326.f},{61.f,45.f,119.f},{13.f,30.f,23.f}};

// correctly-rounded f32 exp (f64 exp, rounded once) — matches numpy f32 exp
__device__ __forceinline__ float expcr(float x) { return (float)exp((double)x); }
// numpy-style f32 sigmoid: op-by-op 1/(1+exp(-x)), each op f32 correctly rounded
__device__ __forceinline__ float sigf(float x) {
    float e = expcr(-x);
    return __fdiv_rn(1.0f, __fadd_rn(1.0f, e));
}

// locate anchor idx -> level geometry + channel-0 pointer (stride hw between channels)
__device__ __forceinline__ const float* locate(const float* f0, const float* f1, const float* f2,
                                               int img, int idx,
                                               int& level, int& hw, int& W, int& hrow, int& wcol, int& a) {
    int local, cell;
    const float* base;
    if (idx < L0END) {
        level = 0; local = idx; hw = 169; W = 13;
        base = f0 + (size_t)img * 43095;        // 255*169
    } else if (idx < L1END) {
        level = 1; local = idx - L0END; hw = 676; W = 26;
        base = f1 + (size_t)img * 172380;       // 255*676
    } else {
        level = 2; local = idx - L1END; hw = 2704; W = 52;
        base = f2 + (size_t)img * 689520;       // 255*2704
    }
    a = local / hw; cell = local - a * hw;
    hrow = cell / W; wcol = cell - hrow * W;
    return base + (size_t)(a * 85) * hw + cell;
}

// ---------------- kernel 1: numpy-f32 score + wave-aggregated compaction ----------------
__global__ void score_kernel(const float* __restrict__ f0, const float* __restrict__ f1,
                             const float* __restrict__ f2,
                             unsigned int* __restrict__ counters,
                             unsigned long long* __restrict__ keys) {
    int t = blockIdx.x * blockDim.x + threadIdx.x;
    int lane = threadIdx.x & 63;

    bool pred[4] = {false, false, false, false};
    unsigned int kidx[4];
    float kscore[4];
    int img;

    if (t < 32 * 512) {
        // ---- level 0, scalar ----
        img = t >> 9;
        int r = t & 511;
        if (r < 507) {
            int a = r / 169, cell = r - a * 169;
            const float* p = f0 + (size_t)img * 43095 + (size_t)(a * 85) * 169 + cell;
            float obj = sigf(p[4 * 169]);
            float mx = p[5 * 169];
            #pragma unroll 8
            for (int c = 1; c < NUM_CLASSES; ++c) {
                float v = p[(5 + c) * 169];
                if (v > mx) mx = v;
            }
            float s = __fmul_rn(obj, sigf(mx));
            if (s >= 0.5f) { pred[0] = true; kidx[0] = r; kscore[0] = s; }
        }
    } else if (t < 64 * 512) {
        // ---- level 1, float4 (hw=676, strides %4==0 -> 16B aligned) ----
        int tt = t - 32 * 512;
        img = tt >> 9;
        int r = tt & 511;
        if (r < 507) {
            int a = r / 169, grp = r - a * 169;
            int cell0 = grp * 4;
            const float* p0 = f1 + (size_t)img * 172380 + (size_t)(a * 85) * 676 + cell0;
            float4 o4 = *(const float4*)(p0 + 4 * 676);
            float4 mx = *(const float4*)(p0 + 5 * 676);
            #pragma unroll 8
            for (int c = 1; c < NUM_CLASSES; ++c) {
                float4 v = *(const float4*)(p0 + (5 + c) * 676);
                mx.x = fmaxf(mx.x, v.x); mx.y = fmaxf(mx.y, v.y);
                mx.z = fmaxf(mx.z, v.z); mx.w = fmaxf(mx.w, v.w);
            }
            float ob[4] = {o4.x, o4.y, o4.z, o4.w};
            float mv[4] = {mx.x, mx.y, mx.z, mx.w};
            #pragma unroll
            for (int j = 0; j < 4; ++j) {
                float s = __fmul_rn(sigf(ob[j]), sigf(mv[j]));
                if (s >= 0.5f) { pred[j] = true; kidx[j] = L0END + a * 676 + cell0 + j; kscore[j] = s; }
            }
        }
    } else {
        // ---- level 2, float4 (hw=2704) ----
        int tt = t - 64 * 512;
        img = tt >> 11;
        int r = tt & 2047;
        if (r < 2028) {
            int a = r / 676, grp = r - a * 676;
            int cell0 = grp * 4;
            const float* p0 = f2 + (size_t)img * 689520 + (size_t)(a * 85) * 2704 + cell0;
            float4 o4 = *(const float4*)(p0 + 4 * 2704);
            float4 mx = *(const float4*)(p0 + 5 * 2704);
            #pragma unroll 8
            for (int c = 1; c < NUM_CLASSES; ++c) {
                float4 v = *(const float4*)(p0 + (5 + c) * 2704);
                mx.x = fmaxf(mx.x, v.x); mx.y = fmaxf(mx.y, v.y);
                mx.z = fmaxf(mx.z, v.z); mx.w = fmaxf(mx.w, v.w);
            }
            float ob[4] = {o4.x, o4.y, o4.z, o4.w};
            float mv[4] = {mx.x, mx.y, mx.z, mx.w};
            #pragma unroll
            for (int j = 0; j < 4; ++j) {
                float s = __fmul_rn(sigf(ob[j]), sigf(mv[j]));
                if (s >= 0.5f) { pred[j] = true; kidx[j] = L1END + a * 2704 + cell0 + j; kscore[j] = s; }
            }
        }
    }

    // wave-aggregated compaction (a wave never spans two images)
    unsigned long long* kout = keys + (size_t)img * NTOT;
    unsigned int* ctr = &counters[img * CTR_STRIDE];
    #pragma unroll
    for (int j = 0; j < 4; ++j) {
        unsigned long long mask = __ballot(pred[j]);
        if (mask) {
            int lead = __ffsll((long long)mask) - 1;
            unsigned int base = 0;
            if (lane == lead) base = atomicAdd(ctr, (unsigned int)__popcll(mask));
            base = __shfl(base, lead, 64);
            if (pred[j]) {
                unsigned int pos = (unsigned int)__popcll(mask & ((1ULL << lane) - 1ULL));
                kout[base + pos] = ((unsigned long long)__float_as_uint(kscore[j]) << 32)
                                   | (unsigned int)(~kidx[j]);
            }
        }
    }
}

// ---------------- kernel 2: per-image top-300 via bitonic sort of next-pow2(n) ----------------
__global__ __launch_bounds__(1024) void topk_kernel(const unsigned int* __restrict__ counters,
                                                    const unsigned long long* __restrict__ keys,
                                                    unsigned int* __restrict__ top_idx) {
    __shared__ unsigned long long s[NPADMAX];   // 128 KiB
    int img = blockIdx.x;
    int tid = threadIdx.x;
    int n = (int)counters[img * CTR_STRIDE];
    if (n > NTOT) n = NTOT;
    int NP = 512;
    while (NP < n) NP <<= 1;
    const unsigned long long* k = keys + (size_t)img * NTOT;
    for (int i = tid; i < NP; i += 1024) s[i] = (i < n) ? k[i] : 0ULL;
    __syncthreads();
    for (int kk = 2; kk <= NP; kk <<= 1) {
        for (int j = kk >> 1; j > 0; j >>= 1) {
            for (int t = tid; t < NP; t += 1024) {
                int l = t ^ j;
                if (l > t) {
                    bool desc = ((t & kk) == 0);
                    unsigned long long av = s[t], bv = s[l];
                    if ((av < bv) == desc) { s[t] = bv; s[l] = av; }
                }
            }
            __syncthreads();
        }
    }
    for (int i = tid; i < TOPK; i += 1024) {
        top_idx[img * TOPK + i] = ~((unsigned int)s[i]);   // zero key -> 0xFFFFFFFF sentinel
    }
}

// ---------------- kernel 2.5: wave-per-row decode of the selected 300 ----------------
// row struct (8 floats): x1,y1,x2,y2,score,clsf,unused,unused
__global__ __launch_bounds__(256) void decode_top_kernel(const float* __restrict__ f0,
                                                         const float* __restrict__ f1,
                                                         const float* __restrict__ f2,
                                                         const unsigned int* __restrict__ top_idx,
                                                         float* __restrict__ rows, int nrows) {
    int gw = blockIdx.x * 4 + (threadIdx.x >> 6);
    int lane = threadIdx.x & 63;
    if (gw >= nrows) return;
    int img = gw / TOPK, k = gw - img * TOPK;
    float* row = rows + (size_t)gw * 8;
    unsigned int idx = top_idx[img * TOPK + k];
    if (idx == 0xFFFFFFFFu) {
        if (lane < 8) row[lane] = 0.0f;
        return;
    }
    int level, hw, W, hrow, wcol, a;
    const float* p = locate(f0, f1, f2, img, (int)idx, level, hw, W, hrow, wcol, a);

    // literal per-class sigmoid argmax, wave-parallel, first-max-wins
    float v1 = p[(5 + lane) * hw];
    float bestv = sigf(v1);
    int besti = lane;
    if (lane < 16) {
        float v2 = p[(69 + lane) * hw];
        float sv2 = sigf(v2);
        if (sv2 > bestv) { bestv = sv2; besti = 64 + lane; }   // tie keeps smaller index
    }
    #pragma unroll
    for (int off = 32; off > 0; off >>= 1) {
        float ov = __shfl_xor(bestv, off, 64);
        int oi = __shfl_xor(besti, off, 64);
        if (ov > bestv || (ov == bestv && oi < besti)) { bestv = ov; besti = oi; }
    }

    float tval = (lane < 5) ? p[lane * hw] : 0.0f;
    float tx = __shfl(tval, 0, 64);
    float ty = __shfl(tval, 1, 64);
    float tw = __shfl(tval, 2, 64);
    float th = __shfl(tval, 3, 64);
    float tob = __shfl(tval, 4, 64);

    if (lane == 0) {
        float x = __fdiv_rn(__fadd_rn(sigf(tx), (float)wcol), (float)W);
        float y = __fdiv_rn(__fadd_rn(sigf(ty), (float)hrow), (float)W);   // H == W per level
        float wd = __fdiv_rn(__fmul_rn(expcr(tw), ANCWf[level][a]), 416.0f);
        float ht = __fdiv_rn(__fmul_rn(expcr(th), ANCHf[level][a]), 416.0f);
        float obj = sigf(tob);
        float score = __fmul_rn(obj, bestv);
        if (!(score >= 0.5f)) score = 0.0f;

        float hx = __fmul_rn(wd, 0.5f);
        float hy = __fmul_rn(ht, 0.5f);
        float x1 = __fmul_rn(__fsub_rn(x, hx), 416.0f);
        float y1 = __fmul_rn(__fsub_rn(y, hy), 416.0f);
        float x2 = __fmul_rn(__fadd_rn(x, hx), 416.0f);
        float y2 = __fmul_rn(__fadd_rn(y, hy), 416.0f);

        row[0] = x1; row[1] = y1; row[2] = x2; row[3] = y2;
        row[4] = score; row[5] = (float)besti; row[6] = 0.0f; row[7] = 0.0f;
    }
}

// ---------------- kernel 3: NMS core on decoded rows (2 barriers) ----------------
__global__ __launch_bounds__(NMS_T) void nms_core_kernel(const float* __restrict__ rows,
                                                         float* __restrict__ out) {
    __shared__ float bx0[TOPK], bx1[TOPK], bx2[TOPK], bx3[TOPK];
    __shared__ float bb0[TOPK], bb1[TOPK], bb2[TOPK], bb3[TOPK];
    __shared__ float area[TOPK], sc[TOPK], clsf[TOPK];
    __shared__ unsigned long long sup[TOPK][5];
    __shared__ unsigned long long keepm[5];

    int img = blockIdx.x;
    int tid = threadIdx.x;

    if (tid < TOPK) {
        const float* row = rows + ((size_t)img * TOPK + tid) * 8;
        float x1 = row[0], y1 = row[1], x2 = row[2], y2 = row[3];
        float score = row[4], cf = row[5];
        float off = __fmul_rn(cf, 832.0f);   // 2*INPUT
        bx0[tid] = x1; bx1[tid] = y1; bx2[tid] = x2; bx3[tid] = y2;
        float b0 = __fadd_rn(x1, off), b1 = __fadd_rn(y1, off);
        float b2 = __fadd_rn(x2, off), b3 = __fadd_rn(y2, off);
        bb0[tid] = b0; bb1[tid] = b1; bb2[tid] = b2; bb3[tid] = b3;
        area[tid] = __fmul_rn(__fsub_rn(b2, b0), __fsub_rn(b3, b1));
        sc[tid] = score;
        clsf[tid] = cf;
    }
    __syncthreads();

    // suppression bit-matrix: sup[r] bit j set iff j > r and IoU(r,j) > 0.3
    for (int r = tid; r < TOPK; r += NMS_T) {
        float a0 = bb0[r], a1 = bb1[r], a2 = bb2[r], a3 = bb3[r], aa = area[r];
        for (int w = 0; w < 5; ++w) {
            unsigned long long m = 0ULL;
            int jbase = w * 64;
            int jend = (jbase + 64 < TOPK) ? 64 : (TOPK - jbase);
            for (int jj = 0; jj < jend; ++jj) {
                int j = jbase + jj;
                if (j <= r) continue;
                float ltx = fmaxf(a0, bb0[j]);
                float lty = fmaxf(a1, bb1[j]);
                float rbx = fminf(a2, bb2[j]);
                float rby = fminf(a3, bb3[j]);
                float wx = fmaxf(__fsub_rn(rbx, ltx), 0.0f);
                float wy = fmaxf(__fsub_rn(rby, lty), 0.0f);
                float inter = __fmul_rn(wx, wy);
                float denom = __fadd_rn(__fsub_rn(__fadd_rn(aa, area[j]), inter), 1e-6f);
                float iou = __fdiv_rn(inter, denom);
                if (iou > 0.3f) m |= (1ULL << jj);
            }
            sup[r][w] = m;
        }
    }
    __syncthreads();

    // serial greedy scan over the bit-matrix (exact reference order)
    if (tid == 0) {
        unsigned long long kp0 = ~0ULL, kp1 = ~0ULL, kp2 = ~0ULL, kp3 = ~0ULL, kp4 = ~0ULL;
        for (int i = 0; i < TOPK; ++i) {
            unsigned long long kw;
            switch (i >> 6) {
                case 0: kw = kp0; break; case 1: kw = kp1; break; case 2: kw = kp2; break;
                case 3: kw = kp3; break; default: kw = kp4; break;
            }
            if ((kw >> (i & 63)) & 1ULL) {
                kp0 &= ~sup[i][0]; kp1 &= ~sup[i][1]; kp2 &= ~sup[i][2];
                kp3 &= ~sup[i][3]; kp4 &= ~sup[i][4];
            }
        }
        keepm[0] = kp0; keepm[1] = kp1; keepm[2] = kp2; keepm[3] = kp3; keepm[4] = kp4;
    }
    __syncthreads();

    if (tid < TOPK) {
        bool kept = (keepm[tid >> 6] >> (tid & 63)) & 1ULL;
        float m = (kept && (sc[tid] > 0.0f)) ? 1.0f : 0.0f;
        float* o = out + ((size_t)img * TOPK + tid) * 6;
        o[0] = __fmul_rn(bx0[tid], m);
        o[1] = __fmul_rn(bx1[tid], m);
        o[2] = __fmul_rn(bx2[tid], m);
        o[3] = __fmul_rn(bx3[tid], m);
        o[4] = __fmul_rn(sc[tid], m);
        o[5] = __fmul_rn(clsf[tid], m);
    }
}

extern "C" void kernel_launch(void* const* d_in, const int* in_sizes, int n_in,
                              void* d_out, int out_size, void* d_ws, size_t ws_size,
                              hipStream_t stream) {
    const float* f0 = (const float*)d_in[0];
    const float* f1 = (const float*)d_in[1];
    const float* f2 = (const float*)d_in[2];
    float* out = (float*)d_out;

    int B = in_sizes[0] / 43095;   // 255*13*13 (== 32 for this problem)
    int nrows = B * TOPK;

    // workspace: [counters B*64 u32][top_idx B*300 u32][rows B*300*8 f32][keys B*NTOT u64]
    unsigned int* counters = (unsigned int*)d_ws;
    size_t off1 = (size_t)B * CTR_STRIDE * sizeof(unsigned int);
    unsigned int* top_idx = (unsigned int*)((char*)d_ws + off1);
    size_t off2 = off1 + ((size_t)nrows * sizeof(unsigned int) + 255) / 256 * 256;
    float* rows = (float*)((char*)d_ws + off2);
    size_t off3 = off2 + ((size_t)nrows * 8 * sizeof(float) + 255) / 256 * 256;
    unsigned long long* keys = (unsigned long long*)((char*)d_ws + off3);

    hipMemsetAsync(counters, 0, off1, stream);
    // threads: 32*512 (L0) + 32*512 (L1) + 32*2048 (L2) = 98304
    score_kernel<<<98304 / 256, 256, 0, stream>>>(f0, f1, f2, counters, keys);
    topk_kernel<<<B, 1024, 0, stream>>>(counters, keys, top_idx);
    decode_top_kernel<<<(nrows + 3) / 4, 256, 0, stream>>>(f0, f1, f2, top_idx, rows, nrows);
    nms_core_kernel<<<B, NMS_T, 0, stream>>>(rows, out);
}

// Round 8
// 152.996 us; speedup vs baseline: 11.3334x; 1.6550x over previous
//
#include <hip/hip_runtime.h>
#include <math.h>

// ---------------- problem constants ----------------
#define NUM_CLASSES 80
#define TOPK 300
#define NTOT 10647             // 3*(169+676+2704)
#define L0END 507
#define L1END 2535
#define NMS_T 384
#define CTR_STRIDE 64          // one counter per 256B
#define SELCAP 2048

// level 0: 13x13 (mask 6,7,8), level 1: 26x26 (mask 3,4,5), level 2: 52x52 (mask 0,1,2)
__constant__ float ANCWf[3][3] = {{116.f,156.f,373.f},{30.f,62.f,59.f},{10.f,16.f,33.f}};
__constant__ float ANCHf[3][3] = {{90.f,198.f,326.f},{61.f,45.f,119.f},{13.f,30.f,23.f}};

// correctly-rounded f32 exp (f64 exp, rounded once) — matches numpy f32 exp
__device__ __forceinline__ float expcr(float x) { return (float)exp((double)x); }
// numpy-style f32 sigmoid: op-by-op 1/(1+exp(-x)), each op f32 correctly rounded
__device__ __forceinline__ float sigf(float x) {
    float e = expcr(-x);
    return __fdiv_rn(1.0f, __fadd_rn(1.0f, e));
}

// locate anchor idx -> level geometry + channel-0 pointer (stride hw between channels)
__device__ __forceinline__ const float* locate(const float* f0, const float* f1, const float* f2,
                                               int img, int idx,
                                               int& level, int& hw, int& W, int& hrow, int& wcol, int& a) {
    int local, cell;
    const float* base;
    if (idx < L0END) {
        level = 0; local = idx; hw = 169; W = 13;
        base = f0 + (size_t)img * 43095;        // 255*169
    } else if (idx < L1END) {
        level = 1; local = idx - L0END; hw = 676; W = 26;
        base = f1 + (size_t)img * 172380;       // 255*676
    } else {
        level = 2; local = idx - L1END; hw = 2704; W = 52;
        base = f2 + (size_t)img * 689520;       // 255*2704
    }
    a = local / hw; cell = local - a * hw;
    hrow = cell / W; wcol = cell - hrow * W;
    return base + (size_t)(a * 85) * hw + cell;
}

// ---------------- kernel 1: numpy-f32 score + wave-aggregated compaction ----------------
__global__ void score_kernel(const float* __restrict__ f0, const float* __restrict__ f1,
                             const float* __restrict__ f2,
                             unsigned int* __restrict__ counters,
                             unsigned long long* __restrict__ keys) {
    int t = blockIdx.x * blockDim.x + threadIdx.x;
    int lane = threadIdx.x & 63;

    bool pred[4] = {false, false, false, false};
    unsigned int kidx[4];
    float kscore[4];
    int img;

    if (t < 32 * 512) {
        // ---- level 0, scalar ----
        img = t >> 9;
        int r = t & 511;
        if (r < 507) {
            int a = r / 169, cell = r - a * 169;
            const float* p = f0 + (size_t)img * 43095 + (size_t)(a * 85) * 169 + cell;
            float obj = sigf(p[4 * 169]);
            float mx = p[5 * 169];
            #pragma unroll 8
            for (int c = 1; c < NUM_CLASSES; ++c) {
                float v = p[(5 + c) * 169];
                if (v > mx) mx = v;
            }
            float s = __fmul_rn(obj, sigf(mx));
            if (s >= 0.5f) { pred[0] = true; kidx[0] = r; kscore[0] = s; }
        }
    } else if (t < 64 * 512) {
        // ---- level 1, float4 (hw=676, strides %4==0 -> 16B aligned) ----
        int tt = t - 32 * 512;
        img = tt >> 9;
        int r = tt & 511;
        if (r < 507) {
            int a = r / 169, grp = r - a * 169;
            int cell0 = grp * 4;
            const float* p0 = f1 + (size_t)img * 172380 + (size_t)(a * 85) * 676 + cell0;
            float4 o4 = *(const float4*)(p0 + 4 * 676);
            float4 mx = *(const float4*)(p0 + 5 * 676);
            #pragma unroll 8
            for (int c = 1; c < NUM_CLASSES; ++c) {
                float4 v = *(const float4*)(p0 + (5 + c) * 676);
                mx.x = fmaxf(mx.x, v.x); mx.y = fmaxf(mx.y, v.y);
                mx.z = fmaxf(mx.z, v.z); mx.w = fmaxf(mx.w, v.w);
            }
            float ob[4] = {o4.x, o4.y, o4.z, o4.w};
            float mv[4] = {mx.x, mx.y, mx.z, mx.w};
            #pragma unroll
            for (int j = 0; j < 4; ++j) {
                float s = __fmul_rn(sigf(ob[j]), sigf(mv[j]));
                if (s >= 0.5f) { pred[j] = true; kidx[j] = L0END + a * 676 + cell0 + j; kscore[j] = s; }
            }
        }
    } else {
        // ---- level 2, float4 (hw=2704) ----
        int tt = t - 64 * 512;
        img = tt >> 11;
        int r = tt & 2047;
        if (r < 2028) {
            int a = r / 676, grp = r - a * 676;
            int cell0 = grp * 4;
            const float* p0 = f2 + (size_t)img * 689520 + (size_t)(a * 85) * 2704 + cell0;
            float4 o4 = *(const float4*)(p0 + 4 * 2704);
            float4 mx = *(const float4*)(p0 + 5 * 2704);
            #pragma unroll 8
            for (int c = 1; c < NUM_CLASSES; ++c) {
                float4 v = *(const float4*)(p0 + (5 + c) * 2704);
                mx.x = fmaxf(mx.x, v.x); mx.y = fmaxf(mx.y, v.y);
                mx.z = fmaxf(mx.z, v.z); mx.w = fmaxf(mx.w, v.w);
            }
            float ob[4] = {o4.x, o4.y, o4.z, o4.w};
            float mv[4] = {mx.x, mx.y, mx.z, mx.w};
            #pragma unroll
            for (int j = 0; j < 4; ++j) {
                float s = __fmul_rn(sigf(ob[j]), sigf(mv[j]));
                if (s >= 0.5f) { pred[j] = true; kidx[j] = L1END + a * 2704 + cell0 + j; kscore[j] = s; }
            }
        }
    }

    // wave-aggregated compaction (a wave never spans two images)
    unsigned long long* kout = keys + (size_t)img * NTOT;
    unsigned int* ctr = &counters[img * CTR_STRIDE];
    #pragma unroll
    for (int j = 0; j < 4; ++j) {
        unsigned long long mask = __ballot(pred[j]);
        if (mask) {
            int lead = __ffsll((long long)mask) - 1;
            unsigned int base = 0;
            if (lane == lead) base = atomicAdd(ctr, (unsigned int)__popcll(mask));
            base = __shfl(base, lead, 64);
            if (pred[j]) {
                unsigned int pos = (unsigned int)__popcll(mask & ((1ULL << lane) - 1ULL));
                kout[base + pos] = ((unsigned long long)__float_as_uint(kscore[j]) << 32)
                                   | (unsigned int)(~kidx[j]);
            }
        }
    }
}

// ---------------- kernel 2: top-300 via histogram select + exact rank ----------------
// score in [0.5,1] -> bits in [0x3F000000,0x3F800000]; bin = monotone 10-bit slice.
// Keys are unique (idx embedded), so pairwise-rank is a permutation and ordering
// matches the full descending sort with (score desc, idx asc) ties.
__global__ __launch_bounds__(1024) void topk_kernel(const unsigned int* __restrict__ counters,
                                                    const unsigned long long* __restrict__ keys,
                                                    unsigned int* __restrict__ top_idx) {
    __shared__ unsigned int hist[1024];
    __shared__ unsigned int scan[1024];
    __shared__ unsigned long long sel[SELCAP];
    __shared__ unsigned int cnt;
    __shared__ int Tbin;

    int img = blockIdx.x;
    int tid = threadIdx.x;
    int n = (int)counters[img * CTR_STRIDE];
    if (n > NTOT) n = NTOT;
    const unsigned long long* k = keys + (size_t)img * NTOT;

    hist[tid] = 0;
    if (tid == 0) { cnt = 0; Tbin = 0; }
    // sentinel-prefill outputs (overwritten by scatter below)
    for (int i = tid; i < TOPK; i += 1024) top_idx[img * TOPK + i] = 0xFFFFFFFFu;
    __syncthreads();

    for (int i = tid; i < n; i += 1024) {
        unsigned int sb = (unsigned int)(k[i] >> 32);
        int bin = (int)((sb - 0x3F000000u) >> 13);
        if (bin > 1023) bin = 1023;
        atomicAdd(&hist[bin], 1u);
    }
    __syncthreads();

    // suffix sums: scan[b] = sum_{b' >= b} hist[b']
    scan[tid] = hist[tid];
    __syncthreads();
    for (int off = 1; off < 1024; off <<= 1) {
        unsigned int v = (tid + off < 1024) ? scan[tid + off] : 0u;
        __syncthreads();
        scan[tid] += v;
        __syncthreads();
    }
    // T = unique bin with scan[T] >= 300 and scan[T+1] < 300 (default 0: take all)
    {
        unsigned int snext = (tid < 1023) ? scan[tid + 1] : 0u;
        if (scan[tid] >= TOPK && snext < TOPK) Tbin = tid;
    }
    __syncthreads();
    int T = Tbin;

    // compact keys with bin >= T (count = scan[T] in [300, 300+hist[T]) or n if n<300)
    for (int i = tid; i < n; i += 1024) {
        unsigned long long kv = k[i];
        unsigned int sb = (unsigned int)(kv >> 32);
        int bin = (int)((sb - 0x3F000000u) >> 13);
        if (bin > 1023) bin = 1023;
        if (bin >= T) {
            unsigned int pos = atomicAdd(&cnt, 1u);
            if (pos < SELCAP) sel[pos] = kv;
        }
    }
    __syncthreads();
    int m = (int)cnt; if (m > SELCAP) m = SELCAP;

    // exact rank by pairwise comparison (keys unique), scatter rank < 300
    for (int i = tid; i < m; i += 1024) {
        unsigned long long ki = sel[i];
        int rank = 0;
        for (int j = 0; j < m; ++j) rank += (sel[j] > ki);
        if (rank < TOPK) top_idx[img * TOPK + rank] = ~((unsigned int)ki);
    }
}

// ---------------- kernel 2.5: wave-per-row decode of the selected 300 ----------------
// row struct (8 floats): x1,y1,x2,y2,score,clsf,unused,unused
__global__ __launch_bounds__(256) void decode_top_kernel(const float* __restrict__ f0,
                                                         const float* __restrict__ f1,
                                                         const float* __restrict__ f2,
                                                         const unsigned int* __restrict__ top_idx,
                                                         float* __restrict__ rows, int nrows) {
    int gw = blockIdx.x * 4 + (threadIdx.x >> 6);
    int lane = threadIdx.x & 63;
    if (gw >= nrows) return;
    int img = gw / TOPK, k = gw - img * TOPK;
    float* row = rows + (size_t)gw * 8;
    unsigned int idx = top_idx[img * TOPK + k];
    if (idx == 0xFFFFFFFFu) {
        if (lane < 8) row[lane] = 0.0f;
        return;
    }
    int level, hw, W, hrow, wcol, a;
    const float* p = locate(f0, f1, f2, img, (int)idx, level, hw, W, hrow, wcol, a);

    // literal per-class sigmoid argmax, wave-parallel, first-max-wins
    float v1 = p[(5 + lane) * hw];
    float bestv = sigf(v1);
    int besti = lane;
    if (lane < 16) {
        float v2 = p[(69 + lane) * hw];
        float sv2 = sigf(v2);
        if (sv2 > bestv) { bestv = sv2; besti = 64 + lane; }   // tie keeps smaller index
    }
    #pragma unroll
    for (int off = 32; off > 0; off >>= 1) {
        float ov = __shfl_xor(bestv, off, 64);
        int oi = __shfl_xor(besti, off, 64);
        if (ov > bestv || (ov == bestv && oi < besti)) { bestv = ov; besti = oi; }
    }

    float tval = (lane < 5) ? p[lane * hw] : 0.0f;
    float tx = __shfl(tval, 0, 64);
    float ty = __shfl(tval, 1, 64);
    float tw = __shfl(tval, 2, 64);
    float th = __shfl(tval, 3, 64);
    float tob = __shfl(tval, 4, 64);

    if (lane == 0) {
        float x = __fdiv_rn(__fadd_rn(sigf(tx), (float)wcol), (float)W);
        float y = __fdiv_rn(__fadd_rn(sigf(ty), (float)hrow), (float)W);   // H == W per level
        float wd = __fdiv_rn(__fmul_rn(expcr(tw), ANCWf[level][a]), 416.0f);
        float ht = __fdiv_rn(__fmul_rn(expcr(th), ANCHf[level][a]), 416.0f);
        float obj = sigf(tob);
        float score = __fmul_rn(obj, bestv);
        if (!(score >= 0.5f)) score = 0.0f;

        float hx = __fmul_rn(wd, 0.5f);
        float hy = __fmul_rn(ht, 0.5f);
        float x1 = __fmul_rn(__fsub_rn(x, hx), 416.0f);
        float y1 = __fmul_rn(__fsub_rn(y, hy), 416.0f);
        float x2 = __fmul_rn(__fadd_rn(x, hx), 416.0f);
        float y2 = __fmul_rn(__fadd_rn(y, hy), 416.0f);

        row[0] = x1; row[1] = y1; row[2] = x2; row[3] = y2;
        row[4] = score; row[5] = (float)besti; row[6] = 0.0f; row[7] = 0.0f;
    }
}

// ---------------- kernel 3: NMS core on decoded rows (2 barriers) ----------------
__global__ __launch_bounds__(NMS_T) void nms_core_kernel(const float* __restrict__ rows,
                                                         float* __restrict__ out) {
    __shared__ float bx0[TOPK], bx1[TOPK], bx2[TOPK], bx3[TOPK];
    __shared__ float bb0[TOPK], bb1[TOPK], bb2[TOPK], bb3[TOPK];
    __shared__ float area[TOPK], sc[TOPK], clsf[TOPK];
    __shared__ unsigned long long sup[TOPK][5];
    __shared__ unsigned long long keepm[5];

    int img = blockIdx.x;
    int tid = threadIdx.x;

    if (tid < TOPK) {
        const float* row = rows + ((size_t)img * TOPK + tid) * 8;
        float x1 = row[0], y1 = row[1], x2 = row[2], y2 = row[3];
        float score = row[4], cf = row[5];
        float off = __fmul_rn(cf, 832.0f);   // 2*INPUT
        bx0[tid] = x1; bx1[tid] = y1; bx2[tid] = x2; bx3[tid] = y2;
        float b0 = __fadd_rn(x1, off), b1 = __fadd_rn(y1, off);
        float b2 = __fadd_rn(x2, off), b3 = __fadd_rn(y2, off);
        bb0[tid] = b0; bb1[tid] = b1; bb2[tid] = b2; bb3[tid] = b3;
        area[tid] = __fmul_rn(__fsub_rn(b2, b0), __fsub_rn(b3, b1));
        sc[tid] = score;
        clsf[tid] = cf;
    }
    __syncthreads();

    // suppression bit-matrix: sup[r] bit j set iff j > r and IoU(r,j) > 0.3
    for (int r = tid; r < TOPK; r += NMS_T) {
        float a0 = bb0[r], a1 = bb1[r], a2 = bb2[r], a3 = bb3[r], aa = area[r];
        for (int w = 0; w < 5; ++w) {
            unsigned long long m = 0ULL;
            int jbase = w * 64;
            int jend = (jbase + 64 < TOPK) ? 64 : (TOPK - jbase);
            for (int jj = 0; jj < jend; ++jj) {
                int j = jbase + jj;
                if (j <= r) continue;
                float ltx = fmaxf(a0, bb0[j]);
                float lty = fmaxf(a1, bb1[j]);
                float rbx = fminf(a2, bb2[j]);
                float rby = fminf(a3, bb3[j]);
                float wx = fmaxf(__fsub_rn(rbx, ltx), 0.0f);
                float wy = fmaxf(__fsub_rn(rby, lty), 0.0f);
                float inter = __fmul_rn(wx, wy);
                float denom = __fadd_rn(__fsub_rn(__fadd_rn(aa, area[j]), inter), 1e-6f);
                float iou = __fdiv_rn(inter, denom);
                if (iou > 0.3f) m |= (1ULL << jj);
            }
            sup[r][w] = m;
        }
    }
    __syncthreads();

    // serial greedy scan over the bit-matrix (exact reference order)
    if (tid == 0) {
        unsigned long long kp0 = ~0ULL, kp1 = ~0ULL, kp2 = ~0ULL, kp3 = ~0ULL, kp4 = ~0ULL;
        for (int i = 0; i < TOPK; ++i) {
            unsigned long long kw;
            switch (i >> 6) {
                case 0: kw = kp0; break; case 1: kw = kp1; break; case 2: kw = kp2; break;
                case 3: kw = kp3; break; default: kw = kp4; break;
            }
            if ((kw >> (i & 63)) & 1ULL) {
                kp0 &= ~sup[i][0]; kp1 &= ~sup[i][1]; kp2 &= ~sup[i][2];
                kp3 &= ~sup[i][3]; kp4 &= ~sup[i][4];
            }
        }
        keepm[0] = kp0; keepm[1] = kp1; keepm[2] = kp2; keepm[3] = kp3; keepm[4] = kp4;
    }
    __syncthreads();

    if (tid < TOPK) {
        bool kept = (keepm[tid >> 6] >> (tid & 63)) & 1ULL;
        float m = (kept && (sc[tid] > 0.0f)) ? 1.0f : 0.0f;
        float* o = out + ((size_t)img * TOPK + tid) * 6;
        o[0] = __fmul_rn(bx0[tid], m);
        o[1] = __fmul_rn(bx1[tid], m);
        o[2] = __fmul_rn(bx2[tid], m);
        o[3] = __fmul_rn(bx3[tid], m);
        o[4] = __fmul_rn(sc[tid], m);
        o[5] = __fmul_rn(clsf[tid], m);
    }
}

extern "C" void kernel_launch(void* const* d_in, const int* in_sizes, int n_in,
                              void* d_out, int out_size, void* d_ws, size_t ws_size,
                              hipStream_t stream) {
    const float* f0 = (const float*)d_in[0];
    const float* f1 = (const float*)d_in[1];
    const float* f2 = (const float*)d_in[2];
    float* out = (float*)d_out;

    int B = in_sizes[0] / 43095;   // 255*13*13 (== 32 for this problem)
    int nrows = B * TOPK;

    // workspace: [counters B*64 u32][top_idx B*300 u32][rows B*300*8 f32][keys B*NTOT u64]
    unsigned int* counters = (unsigned int*)d_ws;
    size_t off1 = (size_t)B * CTR_STRIDE * sizeof(unsigned int);
    unsigned int* top_idx = (unsigned int*)((char*)d_ws + off1);
    size_t off2 = off1 + ((size_t)nrows * sizeof(unsigned int) + 255) / 256 * 256;
    float* rows = (float*)((char*)d_ws + off2);
    size_t off3 = off2 + ((size_t)nrows * 8 * sizeof(float) + 255) / 256 * 256;
    unsigned long long* keys = (unsigned long long*)((char*)d_ws + off3);

    hipMemsetAsync(counters, 0, off1, stream);
    // threads: 32*512 (L0) + 32*512 (L1) + 32*2048 (L2) = 98304
    score_kernel<<<98304 / 256, 256, 0, stream>>>(f0, f1, f2, counters, keys);
    topk_kernel<<<B, 1024, 0, stream>>>(counters, keys, top_idx);
    decode_top_kernel<<<(nrows + 3) / 4, 256, 0, stream>>>(f0, f1, f2, top_idx, rows, nrows);
    nms_core_kernel<<<B, NMS_T, 0, stream>>>(rows, out);
}

// Round 9
// 118.346 us; speedup vs baseline: 14.6517x; 1.2928x over previous
//
#include <hip/hip_runtime.h>
#include <math.h>

// ---------------- problem constants ----------------
#define NUM_CLASSES 80
#define TOPK 300
#define NTOT 10647             // 3*(169+676+2704)
#define L0END 507
#define L1END 2535
#define CTR_STRIDE 64          // one counter per 256B
#define SELCAP 2048

// level 0: 13x13 (mask 6,7,8), level 1: 26x26 (mask 3,4,5), level 2: 52x52 (mask 0,1,2)
__constant__ float ANCWf[3][3] = {{116.f,156.f,373.f},{30.f,62.f,59.f},{10.f,16.f,33.f}};
__constant__ float ANCHf[3][3] = {{90.f,198.f,326.f},{61.f,45.f,119.f},{13.f,30.f,23.f}};

// correctly-rounded f32 exp (f64 exp, rounded once) — matches numpy f32 exp
__device__ __forceinline__ float expcr(float x) { return (float)exp((double)x); }
// numpy-style f32 sigmoid: op-by-op 1/(1+exp(-x)), each op f32 correctly rounded
__device__ __forceinline__ float sigf(float x) {
    float e = expcr(-x);
    return __fdiv_rn(1.0f, __fadd_rn(1.0f, e));
}

// locate anchor idx -> level geometry + channel-0 pointer (stride hw between channels)
__device__ __forceinline__ const float* locate(const float* f0, const float* f1, const float* f2,
                                               int img, int idx,
                                               int& level, int& hw, int& W, int& hrow, int& wcol, int& a) {
    int local, cell;
    const float* base;
    if (idx < L0END) {
        level = 0; local = idx; hw = 169; W = 13;
        base = f0 + (size_t)img * 43095;        // 255*169
    } else if (idx < L1END) {
        level = 1; local = idx - L0END; hw = 676; W = 26;
        base = f1 + (size_t)img * 172380;       // 255*676
    } else {
        level = 2; local = idx - L1END; hw = 2704; W = 52;
        base = f2 + (size_t)img * 689520;       // 255*2704
    }
    a = local / hw; cell = local - a * hw;
    hrow = cell / W; wcol = cell - hrow * W;
    return base + (size_t)(a * 85) * hw + cell;
}

// ---------------- kernel 1: numpy-f32 score + wave-aggregated compaction ----------------
__global__ void score_kernel(const float* __restrict__ f0, const float* __restrict__ f1,
                             const float* __restrict__ f2,
                             unsigned int* __restrict__ counters,
                             unsigned long long* __restrict__ keys) {
    int t = blockIdx.x * blockDim.x + threadIdx.x;
    int lane = threadIdx.x & 63;

    bool pred[4] = {false, false, false, false};
    unsigned int kidx[4];
    float kscore[4];
    int img;

    if (t < 32 * 512) {
        // ---- level 0, scalar ----
        img = t >> 9;
        int r = t & 511;
        if (r < 507) {
            int a = r / 169, cell = r - a * 169;
            const float* p = f0 + (size_t)img * 43095 + (size_t)(a * 85) * 169 + cell;
            float obj = sigf(p[4 * 169]);
            float mx = p[5 * 169];
            #pragma unroll 8
            for (int c = 1; c < NUM_CLASSES; ++c) {
                float v = p[(5 + c) * 169];
                if (v > mx) mx = v;
            }
            float s = __fmul_rn(obj, sigf(mx));
            if (s >= 0.5f) { pred[0] = true; kidx[0] = r; kscore[0] = s; }
        }
    } else if (t < 64 * 512) {
        // ---- level 1, float4 (hw=676, strides %4==0 -> 16B aligned) ----
        int tt = t - 32 * 512;
        img = tt >> 9;
        int r = tt & 511;
        if (r < 507) {
            int a = r / 169, grp = r - a * 169;
            int cell0 = grp * 4;
            const float* p0 = f1 + (size_t)img * 172380 + (size_t)(a * 85) * 676 + cell0;
            float4 o4 = *(const float4*)(p0 + 4 * 676);
            float4 mx = *(const float4*)(p0 + 5 * 676);
            #pragma unroll 8
            for (int c = 1; c < NUM_CLASSES; ++c) {
                float4 v = *(const float4*)(p0 + (5 + c) * 676);
                mx.x = fmaxf(mx.x, v.x); mx.y = fmaxf(mx.y, v.y);
                mx.z = fmaxf(mx.z, v.z); mx.w = fmaxf(mx.w, v.w);
            }
            float ob[4] = {o4.x, o4.y, o4.z, o4.w};
            float mv[4] = {mx.x, mx.y, mx.z, mx.w};
            #pragma unroll
            for (int j = 0; j < 4; ++j) {
                float s = __fmul_rn(sigf(ob[j]), sigf(mv[j]));
                if (s >= 0.5f) { pred[j] = true; kidx[j] = L0END + a * 676 + cell0 + j; kscore[j] = s; }
            }
        }
    } else {
        // ---- level 2, float4 (hw=2704) ----
        int tt = t - 64 * 512;
        img = tt >> 11;
        int r = tt & 2047;
        if (r < 2028) {
            int a = r / 676, grp = r - a * 676;
            int cell0 = grp * 4;
            const float* p0 = f2 + (size_t)img * 689520 + (size_t)(a * 85) * 2704 + cell0;
            float4 o4 = *(const float4*)(p0 + 4 * 2704);
            float4 mx = *(const float4*)(p0 + 5 * 2704);
            #pragma unroll 8
            for (int c = 1; c < NUM_CLASSES; ++c) {
                float4 v = *(const float4*)(p0 + (5 + c) * 2704);
                mx.x = fmaxf(mx.x, v.x); mx.y = fmaxf(mx.y, v.y);
                mx.z = fmaxf(mx.z, v.z); mx.w = fmaxf(mx.w, v.w);
            }
            float ob[4] = {o4.x, o4.y, o4.z, o4.w};
            float mv[4] = {mx.x, mx.y, mx.z, mx.w};
            #pragma unroll
            for (int j = 0; j < 4; ++j) {
                float s = __fmul_rn(sigf(ob[j]), sigf(mv[j]));
                if (s >= 0.5f) { pred[j] = true; kidx[j] = L1END + a * 2704 + cell0 + j; kscore[j] = s; }
            }
        }
    }

    // wave-aggregated compaction (a wave never spans two images)
    unsigned long long* kout = keys + (size_t)img * NTOT;
    unsigned int* ctr = &counters[img * CTR_STRIDE];
    #pragma unroll
    for (int j = 0; j < 4; ++j) {
        unsigned long long mask = __ballot(pred[j]);
        if (mask) {
            int lead = __ffsll((long long)mask) - 1;
            unsigned int base = 0;
            if (lane == lead) base = atomicAdd(ctr, (unsigned int)__popcll(mask));
            base = __shfl(base, lead, 64);
            if (pred[j]) {
                unsigned int pos = (unsigned int)__popcll(mask & ((1ULL << lane) - 1ULL));
                kout[base + pos] = ((unsigned long long)__float_as_uint(kscore[j]) << 32)
                                   | (unsigned int)(~kidx[j]);
            }
        }
    }
}

// ---------------- kernel 2: top-300 via histogram select + exact rank ----------------
__global__ __launch_bounds__(1024) void topk_kernel(const unsigned int* __restrict__ counters,
                                                    const unsigned long long* __restrict__ keys,
                                                    unsigned int* __restrict__ top_idx) {
    __shared__ unsigned int hist[1024];
    __shared__ unsigned int scan[1024];
    __shared__ unsigned long long sel[SELCAP];
    __shared__ unsigned int cnt;
    __shared__ int Tbin;

    int img = blockIdx.x;
    int tid = threadIdx.x;
    int n = (int)counters[img * CTR_STRIDE];
    if (n > NTOT) n = NTOT;
    const unsigned long long* k = keys + (size_t)img * NTOT;

    hist[tid] = 0;
    if (tid == 0) { cnt = 0; Tbin = 0; }
    for (int i = tid; i < TOPK; i += 1024) top_idx[img * TOPK + i] = 0xFFFFFFFFu;
    __syncthreads();

    for (int i = tid; i < n; i += 1024) {
        unsigned int sb = (unsigned int)(k[i] >> 32);
        int bin = (int)((sb - 0x3F000000u) >> 13);
        if (bin > 1023) bin = 1023;
        atomicAdd(&hist[bin], 1u);
    }
    __syncthreads();

    scan[tid] = hist[tid];
    __syncthreads();
    for (int off = 1; off < 1024; off <<= 1) {
        unsigned int v = (tid + off < 1024) ? scan[tid + off] : 0u;
        __syncthreads();
        scan[tid] += v;
        __syncthreads();
    }
    {
        unsigned int snext = (tid < 1023) ? scan[tid + 1] : 0u;
        if (scan[tid] >= TOPK && snext < TOPK) Tbin = tid;
    }
    __syncthreads();
    int T = Tbin;

    for (int i = tid; i < n; i += 1024) {
        unsigned long long kv = k[i];
        unsigned int sb = (unsigned int)(kv >> 32);
        int bin = (int)((sb - 0x3F000000u) >> 13);
        if (bin > 1023) bin = 1023;
        if (bin >= T) {
            unsigned int pos = atomicAdd(&cnt, 1u);
            if (pos < SELCAP) sel[pos] = kv;
        }
    }
    __syncthreads();
    int m = (int)cnt; if (m > SELCAP) m = SELCAP;

    for (int i = tid; i < m; i += 1024) {
        unsigned long long ki = sel[i];
        int rank = 0;
        for (int j = 0; j < m; ++j) rank += (sel[j] > ki);
        if (rank < TOPK) top_idx[img * TOPK + rank] = ~((unsigned int)ki);
    }
}

// ---------------- kernel 2.5: wave-per-row decode of the selected 300 ----------------
// row struct (8 floats): x1,y1,x2,y2,score,clsf,unused,unused
__global__ __launch_bounds__(256) void decode_top_kernel(const float* __restrict__ f0,
                                                         const float* __restrict__ f1,
                                                         const float* __restrict__ f2,
                                                         const unsigned int* __restrict__ top_idx,
                                                         float* __restrict__ rows, int nrows) {
    int gw = blockIdx.x * 4 + (threadIdx.x >> 6);
    int lane = threadIdx.x & 63;
    if (gw >= nrows) return;
    int img = gw / TOPK, k = gw - img * TOPK;
    float* row = rows + (size_t)gw * 8;
    unsigned int idx = top_idx[img * TOPK + k];
    if (idx == 0xFFFFFFFFu) {
        if (lane < 8) row[lane] = 0.0f;
        return;
    }
    int level, hw, W, hrow, wcol, a;
    const float* p = locate(f0, f1, f2, img, (int)idx, level, hw, W, hrow, wcol, a);

    // literal per-class sigmoid argmax, wave-parallel, first-max-wins
    float v1 = p[(5 + lane) * hw];
    float bestv = sigf(v1);
    int besti = lane;
    if (lane < 16) {
        float v2 = p[(69 + lane) * hw];
        float sv2 = sigf(v2);
        if (sv2 > bestv) { bestv = sv2; besti = 64 + lane; }   // tie keeps smaller index
    }
    #pragma unroll
    for (int off = 32; off > 0; off >>= 1) {
        float ov = __shfl_xor(bestv, off, 64);
        int oi = __shfl_xor(besti, off, 64);
        if (ov > bestv || (ov == bestv && oi < besti)) { bestv = ov; besti = oi; }
    }

    float tval = (lane < 5) ? p[lane * hw] : 0.0f;
    float tx = __shfl(tval, 0, 64);
    float ty = __shfl(tval, 1, 64);
    float tw = __shfl(tval, 2, 64);
    float th = __shfl(tval, 3, 64);
    float tob = __shfl(tval, 4, 64);

    if (lane == 0) {
        float x = __fdiv_rn(__fadd_rn(sigf(tx), (float)wcol), (float)W);
        float y = __fdiv_rn(__fadd_rn(sigf(ty), (float)hrow), (float)W);   // H == W per level
        float wd = __fdiv_rn(__fmul_rn(expcr(tw), ANCWf[level][a]), 416.0f);
        float ht = __fdiv_rn(__fmul_rn(expcr(th), ANCHf[level][a]), 416.0f);
        float obj = sigf(tob);
        float score = __fmul_rn(obj, bestv);
        if (!(score >= 0.5f)) score = 0.0f;

        float hx = __fmul_rn(wd, 0.5f);
        float hy = __fmul_rn(ht, 0.5f);
        float x1 = __fmul_rn(__fsub_rn(x, hx), 416.0f);
        float y1 = __fmul_rn(__fsub_rn(y, hy), 416.0f);
        float x2 = __fmul_rn(__fadd_rn(x, hx), 416.0f);
        float y2 = __fmul_rn(__fadd_rn(y, hy), 416.0f);

        row[0] = x1; row[1] = y1; row[2] = x2; row[3] = y2;
        row[4] = score; row[5] = (float)besti; row[6] = 0.0f; row[7] = 0.0f;
    }
}

// ---------------- kernel 3: NMS core — ballot bit-matrix + register/shfl scan ----------------
__global__ __launch_bounds__(512) void nms_core_kernel(const float* __restrict__ rows,
                                                       float* __restrict__ out) {
    __shared__ float bx0[TOPK], bx1[TOPK], bx2[TOPK], bx3[TOPK];
    __shared__ float bb0[TOPK], bb1[TOPK], bb2[TOPK], bb3[TOPK];
    __shared__ float area[TOPK], sc[TOPK], clsf[TOPK];
    __shared__ unsigned long long sup[TOPK][5];
    __shared__ unsigned long long keepm[5];

    int img = blockIdx.x;
    int tid = threadIdx.x;
    int wave = tid >> 6, lane = tid & 63;

    if (tid < TOPK) {
        const float* row = rows + ((size_t)img * TOPK + tid) * 8;
        float x1 = row[0], y1 = row[1], x2 = row[2], y2 = row[3];
        float score = row[4], cf = row[5];
        float off = __fmul_rn(cf, 832.0f);   // 2*INPUT
        bx0[tid] = x1; bx1[tid] = y1; bx2[tid] = x2; bx3[tid] = y2;
        float b0 = __fadd_rn(x1, off), b1 = __fadd_rn(y1, off);
        float b2 = __fadd_rn(x2, off), b3 = __fadd_rn(y2, off);
        bb0[tid] = b0; bb1[tid] = b1; bb2[tid] = b2; bb3[tid] = b3;
        area[tid] = __fmul_rn(__fsub_rn(b2, b0), __fsub_rn(b3, b1));
        sc[tid] = score;
        clsf[tid] = cf;
    }
    __syncthreads();

    // suppression bit-matrix, wave-parallel: lane jj of word w handles j = w*64+jj.
    for (int r = wave; r < TOPK; r += 8) {
        float a0 = bb0[r], a1 = bb1[r], a2 = bb2[r], a3 = bb3[r], aa = area[r];
        #pragma unroll
        for (int w = 0; w < 5; ++w) {
            int j = (w << 6) + lane;
            bool bit = false;
            if (j > r && j < TOPK) {
                float ltx = fmaxf(a0, bb0[j]);
                float lty = fmaxf(a1, bb1[j]);
                float rbx = fminf(a2, bb2[j]);
                float rby = fminf(a3, bb3[j]);
                float wx = fmaxf(__fsub_rn(rbx, ltx), 0.0f);
                float wy = fmaxf(__fsub_rn(rby, lty), 0.0f);
                float inter = __fmul_rn(wx, wy);
                float denom = __fadd_rn(__fsub_rn(__fadd_rn(aa, area[j]), inter), 1e-6f);
                float iou = __fdiv_rn(inter, denom);
                bit = (iou > 0.3f);
            }
            unsigned long long m = __ballot(bit);
            if (lane == 0) sup[r][w] = m;
        }
    }
    __syncthreads();

    // greedy scan by wave 0: matrix in registers (lane l owns rows l+64s), shfl broadcast.
    if (wave == 0) {
        unsigned long long srow[5][5];
        #pragma unroll
        for (int s = 0; s < 5; ++s) {
            int r = (s << 6) + lane;
            #pragma unroll
            for (int w = 0; w < 5; ++w)
                srow[s][w] = (r < TOPK) ? sup[r][w] : 0ULL;
        }
        unsigned long long kp[5] = {~0ULL, ~0ULL, ~0ULL, ~0ULL, ~0ULL};
        #pragma unroll
        for (int s = 0; s < 5; ++s) {
            int nii = (s == 4) ? (TOPK - 256) : 64;
            for (int ii = 0; ii < nii; ++ii) {
                unsigned long long r0 = __shfl(srow[s][0], ii, 64);
                unsigned long long r1 = __shfl(srow[s][1], ii, 64);
                unsigned long long r2 = __shfl(srow[s][2], ii, 64);
                unsigned long long r3 = __shfl(srow[s][3], ii, 64);
                unsigned long long r4 = __shfl(srow[s][4], ii, 64);
                if ((kp[s] >> ii) & 1ULL) {
                    kp[0] &= ~r0; kp[1] &= ~r1; kp[2] &= ~r2; kp[3] &= ~r3; kp[4] &= ~r4;
                }
            }
        }
        if (lane == 0) {
            keepm[0] = kp[0]; keepm[1] = kp[1]; keepm[2] = kp[2];
            keepm[3] = kp[3]; keepm[4] = kp[4];
        }
    }
    __syncthreads();

    if (tid < TOPK) {
        bool kept = (keepm[tid >> 6] >> (tid & 63)) & 1ULL;
        float m = (kept && (sc[tid] > 0.0f)) ? 1.0f : 0.0f;
        float* o = out + ((size_t)img * TOPK + tid) * 6;
        o[0] = __fmul_rn(bx0[tid], m);
        o[1] = __fmul_rn(bx1[tid], m);
        o[2] = __fmul_rn(bx2[tid], m);
        o[3] = __fmul_rn(bx3[tid], m);
        o[4] = __fmul_rn(sc[tid], m);
        o[5] = __fmul_rn(clsf[tid], m);
    }
}

extern "C" void kernel_launch(void* const* d_in, const int* in_sizes, int n_in,
                              void* d_out, int out_size, void* d_ws, size_t ws_size,
                              hipStream_t stream) {
    const float* f0 = (const float*)d_in[0];
    const float* f1 = (const float*)d_in[1];
    const float* f2 = (const float*)d_in[2];
    float* out = (float*)d_out;

    int B = in_sizes[0] / 43095;   // 255*13*13 (== 32 for this problem)
    int nrows = B * TOPK;

    // workspace: [counters B*64 u32][top_idx B*300 u32][rows B*300*8 f32][keys B*NTOT u64]
    unsigned int* counters = (unsigned int*)d_ws;
    size_t off1 = (size_t)B * CTR_STRIDE * sizeof(unsigned int);
    unsigned int* top_idx = (unsigned int*)((char*)d_ws + off1);
    size_t off2 = off1 + ((size_t)nrows * sizeof(unsigned int) + 255) / 256 * 256;
    float* rows = (float*)((char*)d_ws + off2);
    size_t off3 = off2 + ((size_t)nrows * 8 * sizeof(float) + 255) / 256 * 256;
    unsigned long long* keys = (unsigned long long*)((char*)d_ws + off3);

    hipMemsetAsync(counters, 0, off1, stream);
    // threads: 32*512 (L0) + 32*512 (L1) + 32*2048 (L2) = 98304
    score_kernel<<<98304 / 256, 256, 0, stream>>>(f0, f1, f2, counters, keys);
    topk_kernel<<<B, 1024, 0, stream>>>(counters, keys, top_idx);
    decode_top_kernel<<<(nrows + 3) / 4, 256, 0, stream>>>(f0, f1, f2, top_idx, rows, nrows);
    nms_core_kernel<<<B, 512, 0, stream>>>(rows, out);
}

// Round 10
// 104.583 us; speedup vs baseline: 16.5799x; 1.1316x over previous
//
#include <hip/hip_runtime.h>
#include <math.h>

// ---------------- problem constants ----------------
#define NUM_CLASSES 80
#define TOPK 300
#define NTOT 10647             // 3*(169+676+2704)
#define L0END 507
#define L1END 2535
#define CTR_STRIDE 64          // one counter per 256B
#define SELCAP 2048

// level 0: 13x13 (mask 6,7,8), level 1: 26x26 (mask 3,4,5), level 2: 52x52 (mask 0,1,2)
__constant__ float ANCWf[3][3] = {{116.f,156.f,373.f},{30.f,62.f,59.f},{10.f,16.f,33.f}};
__constant__ float ANCHf[3][3] = {{90.f,198.f,326.f},{61.f,45.f,119.f},{13.f,30.f,23.f}};

// correctly-rounded f32 exp (f64 exp, rounded once) — matches numpy f32 exp
__device__ __forceinline__ float expcr(float x) { return (float)exp((double)x); }
// numpy-style f32 sigmoid: op-by-op 1/(1+exp(-x)), each op f32 correctly rounded
__device__ __forceinline__ float sigf(float x) {
    float e = expcr(-x);
    return __fdiv_rn(1.0f, __fadd_rn(1.0f, e));
}

// locate anchor idx -> level geometry + channel-0 pointer (stride hw between channels)
__device__ __forceinline__ const float* locate(const float* f0, const float* f1, const float* f2,
                                               int img, int idx,
                                               int& level, int& hw, int& W, int& hrow, int& wcol, int& a) {
    int local, cell;
    const float* base;
    if (idx < L0END) {
        level = 0; local = idx; hw = 169; W = 13;
        base = f0 + (size_t)img * 43095;        // 255*169
    } else if (idx < L1END) {
        level = 1; local = idx - L0END; hw = 676; W = 26;
        base = f1 + (size_t)img * 172380;       // 255*676
    } else {
        level = 2; local = idx - L1END; hw = 2704; W = 52;
        base = f2 + (size_t)img * 689520;       // 255*2704
    }
    a = local / hw; cell = local - a * hw;
    hrow = cell / W; wcol = cell - hrow * W;
    return base + (size_t)(a * 85) * hw + cell;
}

// ---------------- kernel 1: numpy-f32 score + wave-aggregated compaction ----------------
__global__ void score_kernel(const float* __restrict__ f0, const float* __restrict__ f1,
                             const float* __restrict__ f2,
                             unsigned int* __restrict__ counters,
                             unsigned long long* __restrict__ keys) {
    int t = blockIdx.x * blockDim.x + threadIdx.x;
    int lane = threadIdx.x & 63;

    bool pred[4] = {false, false, false, false};
    unsigned int kidx[4];
    float kscore[4];
    int img;

    if (t < 32 * 512) {
        // ---- level 0, scalar ----
        img = t >> 9;
        int r = t & 511;
        if (r < 507) {
            int a = r / 169, cell = r - a * 169;
            const float* p = f0 + (size_t)img * 43095 + (size_t)(a * 85) * 169 + cell;
            float obj = sigf(p[4 * 169]);
            float mx = p[5 * 169];
            #pragma unroll 8
            for (int c = 1; c < NUM_CLASSES; ++c) {
                float v = p[(5 + c) * 169];
                if (v > mx) mx = v;
            }
            float s = __fmul_rn(obj, sigf(mx));
            if (s >= 0.5f) { pred[0] = true; kidx[0] = r; kscore[0] = s; }
        }
    } else if (t < 64 * 512) {
        // ---- level 1, float4 (hw=676, strides %4==0 -> 16B aligned) ----
        int tt = t - 32 * 512;
        img = tt >> 9;
        int r = tt & 511;
        if (r < 507) {
            int a = r / 169, grp = r - a * 169;
            int cell0 = grp * 4;
            const float* p0 = f1 + (size_t)img * 172380 + (size_t)(a * 85) * 676 + cell0;
            float4 o4 = *(const float4*)(p0 + 4 * 676);
            float4 mx = *(const float4*)(p0 + 5 * 676);
            #pragma unroll 8
            for (int c = 1; c < NUM_CLASSES; ++c) {
                float4 v = *(const float4*)(p0 + (5 + c) * 676);
                mx.x = fmaxf(mx.x, v.x); mx.y = fmaxf(mx.y, v.y);
                mx.z = fmaxf(mx.z, v.z); mx.w = fmaxf(mx.w, v.w);
            }
            float ob[4] = {o4.x, o4.y, o4.z, o4.w};
            float mv[4] = {mx.x, mx.y, mx.z, mx.w};
            #pragma unroll
            for (int j = 0; j < 4; ++j) {
                float s = __fmul_rn(sigf(ob[j]), sigf(mv[j]));
                if (s >= 0.5f) { pred[j] = true; kidx[j] = L0END + a * 676 + cell0 + j; kscore[j] = s; }
            }
        }
    } else {
        // ---- level 2, float4 (hw=2704) ----
        int tt = t - 64 * 512;
        img = tt >> 11;
        int r = tt & 2047;
        if (r < 2028) {
            int a = r / 676, grp = r - a * 676;
            int cell0 = grp * 4;
            const float* p0 = f2 + (size_t)img * 689520 + (size_t)(a * 85) * 2704 + cell0;
            float4 o4 = *(const float4*)(p0 + 4 * 2704);
            float4 mx = *(const float4*)(p0 + 5 * 2704);
            #pragma unroll 8
            for (int c = 1; c < NUM_CLASSES; ++c) {
                float4 v = *(const float4*)(p0 + (5 + c) * 2704);
                mx.x = fmaxf(mx.x, v.x); mx.y = fmaxf(mx.y, v.y);
                mx.z = fmaxf(mx.z, v.z); mx.w = fmaxf(mx.w, v.w);
            }
            float ob[4] = {o4.x, o4.y, o4.z, o4.w};
            float mv[4] = {mx.x, mx.y, mx.z, mx.w};
            #pragma unroll
            for (int j = 0; j < 4; ++j) {
                float s = __fmul_rn(sigf(ob[j]), sigf(mv[j]));
                if (s >= 0.5f) { pred[j] = true; kidx[j] = L1END + a * 2704 + cell0 + j; kscore[j] = s; }
            }
        }
    }

    // wave-aggregated compaction (a wave never spans two images)
    unsigned long long* kout = keys + (size_t)img * NTOT;
    unsigned int* ctr = &counters[img * CTR_STRIDE];
    #pragma unroll
    for (int j = 0; j < 4; ++j) {
        unsigned long long mask = __ballot(pred[j]);
        if (mask) {
            int lead = __ffsll((long long)mask) - 1;
            unsigned int base = 0;
            if (lane == lead) base = atomicAdd(ctr, (unsigned int)__popcll(mask));
            base = __shfl(base, lead, 64);
            if (pred[j]) {
                unsigned int pos = (unsigned int)__popcll(mask & ((1ULL << lane) - 1ULL));
                kout[base + pos] = ((unsigned long long)__float_as_uint(kscore[j]) << 32)
                                   | (unsigned int)(~kidx[j]);
            }
        }
    }
}

// ---------------- kernel 2: top-300 via histogram select + exact rank ----------------
__global__ __launch_bounds__(1024) void topk_kernel(const unsigned int* __restrict__ counters,
                                                    const unsigned long long* __restrict__ keys,
                                                    unsigned int* __restrict__ top_idx) {
    __shared__ unsigned int hist[1024];
    __shared__ unsigned int scan[1024];
    __shared__ unsigned long long sel[SELCAP];
    __shared__ unsigned int cnt;
    __shared__ int Tbin;

    int img = blockIdx.x;
    int tid = threadIdx.x;
    int n = (int)counters[img * CTR_STRIDE];
    if (n > NTOT) n = NTOT;
    const unsigned long long* k = keys + (size_t)img * NTOT;

    hist[tid] = 0;
    if (tid == 0) { cnt = 0; Tbin = 0; }
    for (int i = tid; i < TOPK; i += 1024) top_idx[img * TOPK + i] = 0xFFFFFFFFu;
    __syncthreads();

    for (int i = tid; i < n; i += 1024) {
        unsigned int sb = (unsigned int)(k[i] >> 32);
        int bin = (int)((sb - 0x3F000000u) >> 13);
        if (bin > 1023) bin = 1023;
        atomicAdd(&hist[bin], 1u);
    }
    __syncthreads();

    scan[tid] = hist[tid];
    __syncthreads();
    for (int off = 1; off < 1024; off <<= 1) {
        unsigned int v = (tid + off < 1024) ? scan[tid + off] : 0u;
        __syncthreads();
        scan[tid] += v;
        __syncthreads();
    }
    {
        unsigned int snext = (tid < 1023) ? scan[tid + 1] : 0u;
        if (scan[tid] >= TOPK && snext < TOPK) Tbin = tid;
    }
    __syncthreads();
    int T = Tbin;

    for (int i = tid; i < n; i += 1024) {
        unsigned long long kv = k[i];
        unsigned int sb = (unsigned int)(kv >> 32);
        int bin = (int)((sb - 0x3F000000u) >> 13);
        if (bin > 1023) bin = 1023;
        if (bin >= T) {
            unsigned int pos = atomicAdd(&cnt, 1u);
            if (pos < SELCAP) sel[pos] = kv;
        }
    }
    __syncthreads();
    int m = (int)cnt; if (m > SELCAP) m = SELCAP;

    for (int i = tid; i < m; i += 1024) {
        unsigned long long ki = sel[i];
        int rank = 0;
        for (int j = 0; j < m; ++j) rank += (sel[j] > ki);
        if (rank < TOPK) top_idx[img * TOPK + rank] = ~((unsigned int)ki);
    }
}

// ---------------- kernel 2.5: wave-per-row decode of the selected 300 ----------------
// row struct (8 floats): x1,y1,x2,y2,score,clsf,unused,unused
__global__ __launch_bounds__(256) void decode_top_kernel(const float* __restrict__ f0,
                                                         const float* __restrict__ f1,
                                                         const float* __restrict__ f2,
                                                         const unsigned int* __restrict__ top_idx,
                                                         float* __restrict__ rows, int nrows) {
    int gw = blockIdx.x * 4 + (threadIdx.x >> 6);
    int lane = threadIdx.x & 63;
    if (gw >= nrows) return;
    int img = gw / TOPK, k = gw - img * TOPK;
    float* row = rows + (size_t)gw * 8;
    unsigned int idx = top_idx[img * TOPK + k];
    if (idx == 0xFFFFFFFFu) {
        if (lane < 8) row[lane] = 0.0f;
        return;
    }
    int level, hw, W, hrow, wcol, a;
    const float* p = locate(f0, f1, f2, img, (int)idx, level, hw, W, hrow, wcol, a);

    // literal per-class sigmoid argmax, wave-parallel, first-max-wins
    float v1 = p[(5 + lane) * hw];
    float bestv = sigf(v1);
    int besti = lane;
    if (lane < 16) {
        float v2 = p[(69 + lane) * hw];
        float sv2 = sigf(v2);
        if (sv2 > bestv) { bestv = sv2; besti = 64 + lane; }   // tie keeps smaller index
    }
    #pragma unroll
    for (int off = 32; off > 0; off >>= 1) {
        float ov = __shfl_xor(bestv, off, 64);
        int oi = __shfl_xor(besti, off, 64);
        if (ov > bestv || (ov == bestv && oi < besti)) { bestv = ov; besti = oi; }
    }

    float tval = (lane < 5) ? p[lane * hw] : 0.0f;
    float tx = __shfl(tval, 0, 64);
    float ty = __shfl(tval, 1, 64);
    float tw = __shfl(tval, 2, 64);
    float th = __shfl(tval, 3, 64);
    float tob = __shfl(tval, 4, 64);

    if (lane == 0) {
        float x = __fdiv_rn(__fadd_rn(sigf(tx), (float)wcol), (float)W);
        float y = __fdiv_rn(__fadd_rn(sigf(ty), (float)hrow), (float)W);   // H == W per level
        float wd = __fdiv_rn(__fmul_rn(expcr(tw), ANCWf[level][a]), 416.0f);
        float ht = __fdiv_rn(__fmul_rn(expcr(th), ANCHf[level][a]), 416.0f);
        float obj = sigf(tob);
        float score = __fmul_rn(obj, bestv);
        if (!(score >= 0.5f)) score = 0.0f;

        float hx = __fmul_rn(wd, 0.5f);
        float hy = __fmul_rn(ht, 0.5f);
        float x1 = __fmul_rn(__fsub_rn(x, hx), 416.0f);
        float y1 = __fmul_rn(__fsub_rn(y, hy), 416.0f);
        float x2 = __fmul_rn(__fadd_rn(x, hx), 416.0f);
        float y2 = __fmul_rn(__fadd_rn(y, hy), 416.0f);

        row[0] = x1; row[1] = y1; row[2] = x2; row[3] = y2;
        row[4] = score; row[5] = (float)besti; row[6] = 0.0f; row[7] = 0.0f;
    }
}

// ---------------- kernel 3: NMS core — ballot bit-matrix + lane-parallel scan ----------------
__global__ __launch_bounds__(1024) void nms_core_kernel(const float* __restrict__ rows,
                                                        float* __restrict__ out) {
    __shared__ float bx0[TOPK], bx1[TOPK], bx2[TOPK], bx3[TOPK];
    __shared__ float bb0[TOPK], bb1[TOPK], bb2[TOPK], bb3[TOPK];
    __shared__ float area[TOPK], sc[TOPK], clsf[TOPK];
    __shared__ unsigned long long sup[TOPK][5];
    __shared__ unsigned long long keepm[5];

    int img = blockIdx.x;
    int tid = threadIdx.x;
    int wave = tid >> 6, lane = tid & 63;

    if (tid < TOPK) {
        const float* row = rows + ((size_t)img * TOPK + tid) * 8;
        float x1 = row[0], y1 = row[1], x2 = row[2], y2 = row[3];
        float score = row[4], cf = row[5];
        float off = __fmul_rn(cf, 832.0f);   // 2*INPUT
        bx0[tid] = x1; bx1[tid] = y1; bx2[tid] = x2; bx3[tid] = y2;
        float b0 = __fadd_rn(x1, off), b1 = __fadd_rn(y1, off);
        float b2 = __fadd_rn(x2, off), b3 = __fadd_rn(y2, off);
        bb0[tid] = b0; bb1[tid] = b1; bb2[tid] = b2; bb3[tid] = b3;
        area[tid] = __fmul_rn(__fsub_rn(b2, b0), __fsub_rn(b3, b1));
        sc[tid] = score;
        clsf[tid] = cf;
    }
    __syncthreads();

    // suppression bit-matrix, wave-parallel; lane's j-box kept in registers per w.
    #pragma unroll
    for (int w = 0; w < 5; ++w) {
        int j = (w << 6) + lane;
        bool jv = (j < TOPK);
        float j0 = jv ? bb0[j] : 0.0f;
        float j1 = jv ? bb1[j] : 0.0f;
        float j2 = jv ? bb2[j] : 0.0f;
        float j3 = jv ? bb3[j] : 0.0f;
        float ja = jv ? area[j] : 0.0f;
        for (int r = wave; r < TOPK; r += 16) {
            // row r reads are wave-uniform -> LDS broadcast (conflict-free)
            float a0 = bb0[r], a1 = bb1[r], a2 = bb2[r], a3 = bb3[r], aa = area[r];
            bool bit = false;
            if (jv && j > r) {
                float ltx = fmaxf(a0, j0);
                float lty = fmaxf(a1, j1);
                float rbx = fminf(a2, j2);
                float rby = fminf(a3, j3);
                float wx = fmaxf(__fsub_rn(rbx, ltx), 0.0f);
                float wy = fmaxf(__fsub_rn(rby, lty), 0.0f);
                float inter = __fmul_rn(wx, wy);
                float denom = __fadd_rn(__fsub_rn(__fadd_rn(aa, ja), inter), 1e-6f);
                float iou = __fdiv_rn(inter, denom);
                bit = (iou > 0.3f);
            }
            unsigned long long m = __ballot(bit);
            if (lane == 0) sup[r][w] = m;
        }
    }
    __syncthreads();

    // lane-parallel greedy scan by wave 0: lane w (w<5) owns keep-word kp.
    if (wave == 0) {
        unsigned long long kp = ~0ULL;
        for (int i = 0; i < TOPK; ++i) {
            unsigned long long kw = __shfl(kp, i >> 6, 64);
            bool keep_i = (kw >> (i & 63)) & 1ULL;
            if (keep_i && lane < 5) kp &= ~sup[i][lane];
        }
        if (lane < 5) keepm[lane] = kp;
    }
    __syncthreads();

    if (tid < TOPK) {
        bool kept = (keepm[tid >> 6] >> (tid & 63)) & 1ULL;
        float m = (kept && (sc[tid] > 0.0f)) ? 1.0f : 0.0f;
        float* o = out + ((size_t)img * TOPK + tid) * 6;
        o[0] = __fmul_rn(bx0[tid], m);
        o[1] = __fmul_rn(bx1[tid], m);
        o[2] = __fmul_rn(bx2[tid], m);
        o[3] = __fmul_rn(bx3[tid], m);
        o[4] = __fmul_rn(sc[tid], m);
        o[5] = __fmul_rn(clsf[tid], m);
    }
}

extern "C" void kernel_launch(void* const* d_in, const int* in_sizes, int n_in,
                              void* d_out, int out_size, void* d_ws, size_t ws_size,
                              hipStream_t stream) {
    const float* f0 = (const float*)d_in[0];
    const float* f1 = (const float*)d_in[1];
    const float* f2 = (const float*)d_in[2];
    float* out = (float*)d_out;

    int B = in_sizes[0] / 43095;   // 255*13*13 (== 32 for this problem)
    int nrows = B * TOPK;

    // workspace: [counters B*64 u32][top_idx B*300 u32][rows B*300*8 f32][keys B*NTOT u64]
    unsigned int* counters = (unsigned int*)d_ws;
    size_t off1 = (size_t)B * CTR_STRIDE * sizeof(unsigned int);
    unsigned int* top_idx = (unsigned int*)((char*)d_ws + off1);
    size_t off2 = off1 + ((size_t)nrows * sizeof(unsigned int) + 255) / 256 * 256;
    float* rows = (float*)((char*)d_ws + off2);
    size_t off3 = off2 + ((size_t)nrows * 8 * sizeof(float) + 255) / 256 * 256;
    unsigned long long* keys = (unsigned long long*)((char*)d_ws + off3);

    hipMemsetAsync(counters, 0, off1, stream);
    // threads: 32*512 (L0) + 32*512 (L1) + 32*2048 (L2) = 98304
    score_kernel<<<98304 / 256, 256, 0, stream>>>(f0, f1, f2, counters, keys);
    topk_kernel<<<B, 1024, 0, stream>>>(counters, keys, top_idx);
    decode_top_kernel<<<(nrows + 3) / 4, 256, 0, stream>>>(f0, f1, f2, top_idx, rows, nrows);
    nms_core_kernel<<<B, 1024, 0, stream>>>(rows, out);
}

// Round 11
// 102.030 us; speedup vs baseline: 16.9947x; 1.0250x over previous
//
#include <hip/hip_runtime.h>
#include <math.h>

// ---------------- problem constants ----------------
#define NUM_CLASSES 80
#define TOPK 300
#define NTOT 10647             // 3*(169+676+2704)
#define L0END 507
#define L1END 2535
#define SELCAP 2048

// level 0: 13x13 (mask 6,7,8), level 1: 26x26 (mask 3,4,5), level 2: 52x52 (mask 0,1,2)
__constant__ float ANCWf[3][3] = {{116.f,156.f,373.f},{30.f,62.f,59.f},{10.f,16.f,33.f}};
__constant__ float ANCHf[3][3] = {{90.f,198.f,326.f},{61.f,45.f,119.f},{13.f,30.f,23.f}};

// correctly-rounded f32 exp (f64 exp, rounded once) — matches numpy f32 exp
__device__ __forceinline__ float expcr(float x) { return (float)exp((double)x); }
// numpy-style f32 sigmoid: op-by-op 1/(1+exp(-x)), each op f32 correctly rounded
__device__ __forceinline__ float sigf(float x) {
    float e = expcr(-x);
    return __fdiv_rn(1.0f, __fadd_rn(1.0f, e));
}

// locate anchor idx -> level geometry + channel-0 pointer (stride hw between channels)
__device__ __forceinline__ const float* locate(const float* f0, const float* f1, const float* f2,
                                               int img, int idx,
                                               int& level, int& hw, int& W, int& hrow, int& wcol, int& a) {
    int local, cell;
    const float* base;
    if (idx < L0END) {
        level = 0; local = idx; hw = 169; W = 13;
        base = f0 + (size_t)img * 43095;        // 255*169
    } else if (idx < L1END) {
        level = 1; local = idx - L0END; hw = 676; W = 26;
        base = f1 + (size_t)img * 172380;       // 255*676
    } else {
        level = 2; local = idx - L1END; hw = 2704; W = 52;
        base = f2 + (size_t)img * 689520;       // 255*2704
    }
    a = local / hw; cell = local - a * hw;
    hrow = cell / W; wcol = cell - hrow * W;
    return base + (size_t)(a * 85) * hw + cell;
}

// ---------------- kernel 1: numpy-f32 score -> dense key slots (no atomics) ----------------
// keys[img*NTOT+idx] = score>=0.5 ? (score_bits<<32 | ~idx) : 0. Every idx
// written exactly once per call (mapping covers all slots; no memset needed).
__global__ void score_kernel(const float* __restrict__ f0, const float* __restrict__ f1,
                             const float* __restrict__ f2,
                             unsigned long long* __restrict__ keys) {
    int t = blockIdx.x * blockDim.x + threadIdx.x;

    if (t < 32 * 512) {
        // ---- level 0, scalar ----
        int img = t >> 9;
        int r = t & 511;
        if (r < 507) {
            int a = r / 169, cell = r - a * 169;
            const float* p = f0 + (size_t)img * 43095 + (size_t)(a * 85) * 169 + cell;
            float obj = sigf(p[4 * 169]);
            float mx = p[5 * 169];
            #pragma unroll 8
            for (int c = 1; c < NUM_CLASSES; ++c) {
                float v = p[(5 + c) * 169];
                if (v > mx) mx = v;
            }
            float s = __fmul_rn(obj, sigf(mx));
            unsigned long long kv = 0ULL;
            if (s >= 0.5f)
                kv = ((unsigned long long)__float_as_uint(s) << 32) | (unsigned int)(~(unsigned int)r);
            keys[(size_t)img * NTOT + r] = kv;
        }
    } else if (t < 64 * 512) {
        // ---- level 1, float4 (hw=676, strides %4==0 -> 16B aligned) ----
        int tt = t - 32 * 512;
        int img = tt >> 9;
        int r = tt & 511;
        if (r < 507) {
            int a = r / 169, grp = r - a * 169;
            int cell0 = grp * 4;
            const float* p0 = f1 + (size_t)img * 172380 + (size_t)(a * 85) * 676 + cell0;
            float4 o4 = *(const float4*)(p0 + 4 * 676);
            float4 mx = *(const float4*)(p0 + 5 * 676);
            #pragma unroll 8
            for (int c = 1; c < NUM_CLASSES; ++c) {
                float4 v = *(const float4*)(p0 + (5 + c) * 676);
                mx.x = fmaxf(mx.x, v.x); mx.y = fmaxf(mx.y, v.y);
                mx.z = fmaxf(mx.z, v.z); mx.w = fmaxf(mx.w, v.w);
            }
            float ob[4] = {o4.x, o4.y, o4.z, o4.w};
            float mv[4] = {mx.x, mx.y, mx.z, mx.w};
            unsigned long long* kout = keys + (size_t)img * NTOT + (L0END + a * 676 + cell0);
            #pragma unroll
            for (int j = 0; j < 4; ++j) {
                float s = __fmul_rn(sigf(ob[j]), sigf(mv[j]));
                unsigned int idx = L0END + a * 676 + cell0 + j;
                unsigned long long kv = 0ULL;
                if (s >= 0.5f)
                    kv = ((unsigned long long)__float_as_uint(s) << 32) | (unsigned int)(~idx);
                kout[j] = kv;
            }
        }
    } else {
        // ---- level 2, float4 (hw=2704) ----
        int tt = t - 64 * 512;
        int img = tt >> 11;
        int r = tt & 2047;
        if (r < 2028) {
            int a = r / 676, grp = r - a * 676;
            int cell0 = grp * 4;
            const float* p0 = f2 + (size_t)img * 689520 + (size_t)(a * 85) * 2704 + cell0;
            float4 o4 = *(const float4*)(p0 + 4 * 2704);
            float4 mx = *(const float4*)(p0 + 5 * 2704);
            #pragma unroll 8
            for (int c = 1; c < NUM_CLASSES; ++c) {
                float4 v = *(const float4*)(p0 + (5 + c) * 2704);
                mx.x = fmaxf(mx.x, v.x); mx.y = fmaxf(mx.y, v.y);
                mx.z = fmaxf(mx.z, v.z); mx.w = fmaxf(mx.w, v.w);
            }
            float ob[4] = {o4.x, o4.y, o4.z, o4.w};
            float mv[4] = {mx.x, mx.y, mx.z, mx.w};
            unsigned long long* kout = keys + (size_t)img * NTOT + (L1END + a * 2704 + cell0);
            #pragma unroll
            for (int j = 0; j < 4; ++j) {
                float s = __fmul_rn(sigf(ob[j]), sigf(mv[j]));
                unsigned int idx = L1END + a * 2704 + cell0 + j;
                unsigned long long kv = 0ULL;
                if (s >= 0.5f)
                    kv = ((unsigned long long)__float_as_uint(s) << 32) | (unsigned int)(~idx);
                kout[j] = kv;
            }
        }
    }
}

// ---------------- kernel 2: top-300 via histogram select + exact rank ----------------
// score in [0.5,1] -> bits in [0x3F000000,0x3F800000]; signed bin = monotone
// 10-bit slice; zero keys give negative bin and are excluded (T >= 0).
__global__ __launch_bounds__(1024) void topk_kernel(const unsigned long long* __restrict__ keys,
                                                    unsigned int* __restrict__ top_idx) {
    __shared__ unsigned int hist[1024];
    __shared__ unsigned int scan[1024];
    __shared__ unsigned long long sel[SELCAP];
    __shared__ unsigned int cnt;
    __shared__ int Tbin;

    int img = blockIdx.x;
    int tid = threadIdx.x;
    const unsigned long long* k = keys + (size_t)img * NTOT;

    hist[tid] = 0;
    if (tid == 0) { cnt = 0; Tbin = 0; }
    for (int i = tid; i < TOPK; i += 1024) top_idx[img * TOPK + i] = 0xFFFFFFFFu;
    __syncthreads();

    for (int i = tid; i < NTOT; i += 1024) {
        unsigned int sb = (unsigned int)(k[i] >> 32);
        int bin = (int)(sb - 0x3F000000u) >> 13;   // negative for zero keys
        if (bin >= 0) {
            if (bin > 1023) bin = 1023;
            atomicAdd(&hist[bin], 1u);
        }
    }
    __syncthreads();

    scan[tid] = hist[tid];
    __syncthreads();
    for (int off = 1; off < 1024; off <<= 1) {
        unsigned int v = (tid + off < 1024) ? scan[tid + off] : 0u;
        __syncthreads();
        scan[tid] += v;
        __syncthreads();
    }
    {
        unsigned int snext = (tid < 1023) ? scan[tid + 1] : 0u;
        if (scan[tid] >= TOPK && snext < TOPK) Tbin = tid;
    }
    __syncthreads();
    int T = Tbin;

    for (int i = tid; i < NTOT; i += 1024) {
        unsigned long long kv = k[i];
        unsigned int sb = (unsigned int)(kv >> 32);
        int bin = (int)(sb - 0x3F000000u) >> 13;
        if (bin > 1023) bin = 1023;
        if (bin >= T) {
            unsigned int pos = atomicAdd(&cnt, 1u);
            if (pos < SELCAP) sel[pos] = kv;
        }
    }
    __syncthreads();
    int m = (int)cnt; if (m > SELCAP) m = SELCAP;

    for (int i = tid; i < m; i += 1024) {
        unsigned long long ki = sel[i];
        int rank = 0;
        for (int j = 0; j < m; ++j) rank += (sel[j] > ki);
        if (rank < TOPK) top_idx[img * TOPK + rank] = ~((unsigned int)ki);
    }
}

// ---------------- kernel 2.5: wave-per-row decode of the selected 300 ----------------
// row struct (8 floats): x1,y1,x2,y2,score,clsf,unused,unused
__global__ __launch_bounds__(256) void decode_top_kernel(const float* __restrict__ f0,
                                                         const float* __restrict__ f1,
                                                         const float* __restrict__ f2,
                                                         const unsigned int* __restrict__ top_idx,
                                                         float* __restrict__ rows, int nrows) {
    int gw = blockIdx.x * 4 + (threadIdx.x >> 6);
    int lane = threadIdx.x & 63;
    if (gw >= nrows) return;
    int img = gw / TOPK, k = gw - img * TOPK;
    float* row = rows + (size_t)gw * 8;
    unsigned int idx = top_idx[img * TOPK + k];
    if (idx == 0xFFFFFFFFu) {
        if (lane < 8) row[lane] = 0.0f;
        return;
    }
    int level, hw, W, hrow, wcol, a;
    const float* p = locate(f0, f1, f2, img, (int)idx, level, hw, W, hrow, wcol, a);

    // literal per-class sigmoid argmax, wave-parallel, first-max-wins
    float v1 = p[(5 + lane) * hw];
    float bestv = sigf(v1);
    int besti = lane;
    if (lane < 16) {
        float v2 = p[(69 + lane) * hw];
        float sv2 = sigf(v2);
        if (sv2 > bestv) { bestv = sv2; besti = 64 + lane; }   // tie keeps smaller index
    }
    #pragma unroll
    for (int off = 32; off > 0; off >>= 1) {
        float ov = __shfl_xor(bestv, off, 64);
        int oi = __shfl_xor(besti, off, 64);
        if (ov > bestv || (ov == bestv && oi < besti)) { bestv = ov; besti = oi; }
    }

    float tval = (lane < 5) ? p[lane * hw] : 0.0f;
    float tx = __shfl(tval, 0, 64);
    float ty = __shfl(tval, 1, 64);
    float tw = __shfl(tval, 2, 64);
    float th = __shfl(tval, 3, 64);
    float tob = __shfl(tval, 4, 64);

    if (lane == 0) {
        float x = __fdiv_rn(__fadd_rn(sigf(tx), (float)wcol), (float)W);
        float y = __fdiv_rn(__fadd_rn(sigf(ty), (float)hrow), (float)W);   // H == W per level
        float wd = __fdiv_rn(__fmul_rn(expcr(tw), ANCWf[level][a]), 416.0f);
        float ht = __fdiv_rn(__fmul_rn(expcr(th), ANCHf[level][a]), 416.0f);
        float obj = sigf(tob);
        float score = __fmul_rn(obj, bestv);
        if (!(score >= 0.5f)) score = 0.0f;

        float hx = __fmul_rn(wd, 0.5f);
        float hy = __fmul_rn(ht, 0.5f);
        float x1 = __fmul_rn(__fsub_rn(x, hx), 416.0f);
        float y1 = __fmul_rn(__fsub_rn(y, hy), 416.0f);
        float x2 = __fmul_rn(__fadd_rn(x, hx), 416.0f);
        float y2 = __fmul_rn(__fadd_rn(y, hy), 416.0f);

        row[0] = x1; row[1] = y1; row[2] = x2; row[3] = y2;
        row[4] = score; row[5] = (float)besti; row[6] = 0.0f; row[7] = 0.0f;
    }
}

// ---------------- kernel 3: NMS core — ballot bit-matrix + lane-parallel scan ----------------
__global__ __launch_bounds__(1024) void nms_core_kernel(const float* __restrict__ rows,
                                                        float* __restrict__ out) {
    __shared__ float bx0[TOPK], bx1[TOPK], bx2[TOPK], bx3[TOPK];
    __shared__ float bb0[TOPK], bb1[TOPK], bb2[TOPK], bb3[TOPK];
    __shared__ float area[TOPK], sc[TOPK], clsf[TOPK];
    __shared__ unsigned long long sup[TOPK][5];
    __shared__ unsigned long long keepm[5];

    int img = blockIdx.x;
    int tid = threadIdx.x;
    int wave = tid >> 6, lane = tid & 63;

    if (tid < TOPK) {
        const float* row = rows + ((size_t)img * TOPK + tid) * 8;
        float x1 = row[0], y1 = row[1], x2 = row[2], y2 = row[3];
        float score = row[4], cf = row[5];
        float off = __fmul_rn(cf, 832.0f);   // 2*INPUT
        bx0[tid] = x1; bx1[tid] = y1; bx2[tid] = x2; bx3[tid] = y2;
        float b0 = __fadd_rn(x1, off), b1 = __fadd_rn(y1, off);
        float b2 = __fadd_rn(x2, off), b3 = __fadd_rn(y2, off);
        bb0[tid] = b0; bb1[tid] = b1; bb2[tid] = b2; bb3[tid] = b3;
        area[tid] = __fmul_rn(__fsub_rn(b2, b0), __fsub_rn(b3, b1));
        sc[tid] = score;
        clsf[tid] = cf;
    }
    __syncthreads();

    // suppression bit-matrix, wave-parallel; lane's j-box kept in registers per w.
    #pragma unroll
    for (int w = 0; w < 5; ++w) {
        int j = (w << 6) + lane;
        bool jv = (j < TOPK);
        float j0 = jv ? bb0[j] : 0.0f;
        float j1 = jv ? bb1[j] : 0.0f;
        float j2 = jv ? bb2[j] : 0.0f;
        float j3 = jv ? bb3[j] : 0.0f;
        float ja = jv ? area[j] : 0.0f;
        for (int r = wave; r < TOPK; r += 16) {
            // row r reads are wave-uniform -> LDS broadcast (conflict-free)
            float a0 = bb0[r], a1 = bb1[r], a2 = bb2[r], a3 = bb3[r], aa = area[r];
            bool bit = false;
            if (jv && j > r) {
                float ltx = fmaxf(a0, j0);
                float lty = fmaxf(a1, j1);
                float rbx = fminf(a2, j2);
                float rby = fminf(a3, j3);
                float wx = fmaxf(__fsub_rn(rbx, ltx), 0.0f);
                float wy = fmaxf(__fsub_rn(rby, lty), 0.0f);
                float inter = __fmul_rn(wx, wy);
                float denom = __fadd_rn(__fsub_rn(__fadd_rn(aa, ja), inter), 1e-6f);
                float iou = __fdiv_rn(inter, denom);
                bit = (iou > 0.3f);
            }
            unsigned long long m = __ballot(bit);
            if (lane == 0) sup[r][w] = m;
        }
    }
    __syncthreads();

    // lane-parallel greedy scan by wave 0: lane w (w<5) owns keep-word kp.
    if (wave == 0) {
        unsigned long long kp = ~0ULL;
        for (int i = 0; i < TOPK; ++i) {
            unsigned long long kw = __shfl(kp, i >> 6, 64);
            bool keep_i = (kw >> (i & 63)) & 1ULL;
            if (keep_i && lane < 5) kp &= ~sup[i][lane];
        }
        if (lane < 5) keepm[lane] = kp;
    }
    __syncthreads();

    if (tid < TOPK) {
        bool kept = (keepm[tid >> 6] >> (tid & 63)) & 1ULL;
        float m = (kept && (sc[tid] > 0.0f)) ? 1.0f : 0.0f;
        float* o = out + ((size_t)img * TOPK + tid) * 6;
        o[0] = __fmul_rn(bx0[tid], m);
        o[1] = __fmul_rn(bx1[tid], m);
        o[2] = __fmul_rn(bx2[tid], m);
        o[3] = __fmul_rn(bx3[tid], m);
        o[4] = __fmul_rn(sc[tid], m);
        o[5] = __fmul_rn(clsf[tid], m);
    }
}

extern "C" void kernel_launch(void* const* d_in, const int* in_sizes, int n_in,
                              void* d_out, int out_size, void* d_ws, size_t ws_size,
                              hipStream_t stream) {
    const float* f0 = (const float*)d_in[0];
    const float* f1 = (const float*)d_in[1];
    const float* f2 = (const float*)d_in[2];
    float* out = (float*)d_out;

    int B = in_sizes[0] / 43095;   // 255*13*13 (== 32 for this problem)
    int nrows = B * TOPK;

    // workspace: [top_idx B*300 u32][rows B*300*8 f32][keys B*NTOT u64]
    unsigned int* top_idx = (unsigned int*)d_ws;
    size_t off1 = ((size_t)nrows * sizeof(unsigned int) + 255) / 256 * 256;
    float* rows = (float*)((char*)d_ws + off1);
    size_t off2 = off1 + ((size_t)nrows * 8 * sizeof(float) + 255) / 256 * 256;
    unsigned long long* keys = (unsigned long long*)((char*)d_ws + off2);

    // threads: 32*512 (L0) + 32*512 (L1) + 32*2048 (L2) = 98304
    score_kernel<<<98304 / 256, 256, 0, stream>>>(f0, f1, f2, keys);
    topk_kernel<<<B, 1024, 0, stream>>>(keys, top_idx);
    decode_top_kernel<<<(nrows + 3) / 4, 256, 0, stream>>>(f0, f1, f2, top_idx, rows, nrows);
    nms_core_kernel<<<B, 1024, 0, stream>>>(rows, out);
}

// Round 12
// 100.243 us; speedup vs baseline: 17.2976x; 1.0178x over previous
//
#include <hip/hip_runtime.h>
#include <math.h>

// ---------------- problem constants ----------------
#define NUM_CLASSES 80
#define TOPK 300
#define NTOT 10647             // 3*(169+676+2704)
#define L0END 507
#define L1END 2535
#define SELCAP 2048

// level 0: 13x13 (mask 6,7,8), level 1: 26x26 (mask 3,4,5), level 2: 52x52 (mask 0,1,2)
__constant__ float ANCWf[3][3] = {{116.f,156.f,373.f},{30.f,62.f,59.f},{10.f,16.f,33.f}};
__constant__ float ANCHf[3][3] = {{90.f,198.f,326.f},{61.f,45.f,119.f},{13.f,30.f,23.f}};

// correctly-rounded f32 exp (f64 exp, rounded once) — matches numpy f32 exp
__device__ __forceinline__ float expcr(float x) { return (float)exp((double)x); }
// numpy-style f32 sigmoid: op-by-op 1/(1+exp(-x)), each op f32 correctly rounded
__device__ __forceinline__ float sigf(float x) {
    float e = expcr(-x);
    return __fdiv_rn(1.0f, __fadd_rn(1.0f, e));
}

// locate anchor idx -> level geometry + channel-0 pointer (stride hw between channels)
__device__ __forceinline__ const float* locate(const float* f0, const float* f1, const float* f2,
                                               int img, int idx,
                                               int& level, int& hw, int& W, int& hrow, int& wcol, int& a) {
    int local, cell;
    const float* base;
    if (idx < L0END) {
        level = 0; local = idx; hw = 169; W = 13;
        base = f0 + (size_t)img * 43095;        // 255*169
    } else if (idx < L1END) {
        level = 1; local = idx - L0END; hw = 676; W = 26;
        base = f1 + (size_t)img * 172380;       // 255*676
    } else {
        level = 2; local = idx - L1END; hw = 2704; W = 52;
        base = f2 + (size_t)img * 689520;       // 255*2704
    }
    a = local / hw; cell = local - a * hw;
    hrow = cell / W; wcol = cell - hrow * W;
    return base + (size_t)(a * 85) * hw + cell;
}

// ---------------- kernel 1: numpy-f32 score -> dense key slots (no atomics) ----------------
__global__ void score_kernel(const float* __restrict__ f0, const float* __restrict__ f1,
                             const float* __restrict__ f2,
                             unsigned long long* __restrict__ keys) {
    int t = blockIdx.x * blockDim.x + threadIdx.x;

    if (t < 32 * 512) {
        // ---- level 0, scalar ----
        int img = t >> 9;
        int r = t & 511;
        if (r < 507) {
            int a = r / 169, cell = r - a * 169;
            const float* p = f0 + (size_t)img * 43095 + (size_t)(a * 85) * 169 + cell;
            float obj = sigf(p[4 * 169]);
            float mx = p[5 * 169];
            #pragma unroll 16
            for (int c = 1; c < NUM_CLASSES; ++c) {
                float v = p[(5 + c) * 169];
                if (v > mx) mx = v;
            }
            float s = __fmul_rn(obj, sigf(mx));
            unsigned long long kv = 0ULL;
            if (s >= 0.5f)
                kv = ((unsigned long long)__float_as_uint(s) << 32) | (unsigned int)(~(unsigned int)r);
            keys[(size_t)img * NTOT + r] = kv;
        }
    } else if (t < 64 * 512) {
        // ---- level 1, float4 (hw=676, strides %4==0 -> 16B aligned) ----
        int tt = t - 32 * 512;
        int img = tt >> 9;
        int r = tt & 511;
        if (r < 507) {
            int a = r / 169, grp = r - a * 169;
            int cell0 = grp * 4;
            const float* p0 = f1 + (size_t)img * 172380 + (size_t)(a * 85) * 676 + cell0;
            float4 o4 = *(const float4*)(p0 + 4 * 676);
            float4 mx = *(const float4*)(p0 + 5 * 676);
            #pragma unroll 16
            for (int c = 1; c < NUM_CLASSES; ++c) {
                float4 v = *(const float4*)(p0 + (5 + c) * 676);
                mx.x = fmaxf(mx.x, v.x); mx.y = fmaxf(mx.y, v.y);
                mx.z = fmaxf(mx.z, v.z); mx.w = fmaxf(mx.w, v.w);
            }
            float ob[4] = {o4.x, o4.y, o4.z, o4.w};
            float mv[4] = {mx.x, mx.y, mx.z, mx.w};
            unsigned long long* kout = keys + (size_t)img * NTOT + (L0END + a * 676 + cell0);
            #pragma unroll
            for (int j = 0; j < 4; ++j) {
                float s = __fmul_rn(sigf(ob[j]), sigf(mv[j]));
                unsigned int idx = L0END + a * 676 + cell0 + j;
                unsigned long long kv = 0ULL;
                if (s >= 0.5f)
                    kv = ((unsigned long long)__float_as_uint(s) << 32) | (unsigned int)(~idx);
                kout[j] = kv;
            }
        }
    } else {
        // ---- level 2, float4 (hw=2704) ----
        int tt = t - 64 * 512;
        int img = tt >> 11;
        int r = tt & 2047;
        if (r < 2028) {
            int a = r / 676, grp = r - a * 676;
            int cell0 = grp * 4;
            const float* p0 = f2 + (size_t)img * 689520 + (size_t)(a * 85) * 2704 + cell0;
            float4 o4 = *(const float4*)(p0 + 4 * 2704);
            float4 mx = *(const float4*)(p0 + 5 * 2704);
            #pragma unroll 16
            for (int c = 1; c < NUM_CLASSES; ++c) {
                float4 v = *(const float4*)(p0 + (5 + c) * 2704);
                mx.x = fmaxf(mx.x, v.x); mx.y = fmaxf(mx.y, v.y);
                mx.z = fmaxf(mx.z, v.z); mx.w = fmaxf(mx.w, v.w);
            }
            float ob[4] = {o4.x, o4.y, o4.z, o4.w};
            float mv[4] = {mx.x, mx.y, mx.z, mx.w};
            unsigned long long* kout = keys + (size_t)img * NTOT + (L1END + a * 2704 + cell0);
            #pragma unroll
            for (int j = 0; j < 4; ++j) {
                float s = __fmul_rn(sigf(ob[j]), sigf(mv[j]));
                unsigned int idx = L1END + a * 2704 + cell0 + j;
                unsigned long long kv = 0ULL;
                if (s >= 0.5f)
                    kv = ((unsigned long long)__float_as_uint(s) << 32) | (unsigned int)(~idx);
                kout[j] = kv;
            }
        }
    }
}

// ---------------- kernel 2: top-300 — LDS-staged single pass, wave-shuffle scan ----------------
// score in [0.5,1] -> bits in [0x3F000000,0x3F800000]; signed bin = monotone
// 10-bit slice; zero keys give negative bin and are excluded (T >= 0).
__global__ __launch_bounds__(1024) void topk_kernel(const unsigned long long* __restrict__ keys,
                                                    unsigned int* __restrict__ top_idx) {
    __shared__ unsigned long long s[NTOT];      // 85,176 B — staged keys
    __shared__ unsigned int hist[1024];
    __shared__ unsigned long long sel[SELCAP];  // 16 KiB
    __shared__ unsigned int wsum[16], wsuf[16];
    __shared__ unsigned int cnt;
    __shared__ int Tbin;

    int img = blockIdx.x;
    int tid = threadIdx.x;
    int wv = tid >> 6, ln = tid & 63;
    const unsigned long long* k = keys + (size_t)img * NTOT;

    hist[tid] = 0;
    if (tid == 0) { cnt = 0; Tbin = 0; }
    for (int i = tid; i < TOPK; i += 1024) top_idx[img * TOPK + i] = 0xFFFFFFFFu;
    __syncthreads();

    // stage + histogram in one global pass
    for (int i = tid; i < NTOT; i += 1024) {
        unsigned long long kv = k[i];
        s[i] = kv;
        unsigned int sb = (unsigned int)(kv >> 32);
        int bin = (int)(sb - 0x3F000000u) >> 13;   // negative for zero keys
        if (bin >= 0) {
            if (bin > 1023) bin = 1023;
            atomicAdd(&hist[bin], 1u);
        }
    }
    __syncthreads();

    // wave-level suffix scan of hist (scan[b] = sum_{b'>=b} hist[b'])
    unsigned int ssum = hist[tid];
    #pragma unroll
    for (int off = 1; off < 64; off <<= 1) {
        unsigned int o = __shfl_down(ssum, off, 64);
        if (ln + off < 64) ssum += o;
    }
    if (ln == 0) wsum[wv] = ssum;   // note: ssum at lane0 = wave total only for lane 0; per-lane ssum = suffix within wave
    __syncthreads();
    if (wv == 0) {
        unsigned int tws = (ln < 16) ? wsum[ln] : 0u;
        #pragma unroll
        for (int off = 1; off < 16; off <<= 1) {
            unsigned int o = __shfl_down(tws, off, 64);
            if (ln + off < 16) tws += o;
        }
        if (ln < 16) wsuf[ln] = tws;   // wsuf[w] = sum over waves >= w
    }
    __syncthreads();
    unsigned int higher = (wv < 15) ? wsuf[wv + 1] : 0u;
    unsigned int scanval = ssum + higher;                       // suffix sum from this bin
    unsigned int down1 = __shfl_down(scanval, 1, 64);
    unsigned int nextval = (ln < 63) ? down1 : higher;          // scan of bin+1 (tid=1023 -> 0)
    if (scanval >= TOPK && nextval < TOPK) Tbin = tid;          // unique transition
    __syncthreads();
    int T = Tbin;

    // select from LDS: bin >= T
    for (int i = tid; i < NTOT; i += 1024) {
        unsigned long long kv = s[i];
        unsigned int sb = (unsigned int)(kv >> 32);
        int bin = (int)(sb - 0x3F000000u) >> 13;
        if (bin > 1023) bin = 1023;
        if (bin >= T) {
            unsigned int pos = atomicAdd(&cnt, 1u);
            if (pos < SELCAP) sel[pos] = kv;
        }
    }
    __syncthreads();
    int m = (int)cnt; if (m > SELCAP) m = SELCAP;

    // exact rank by pairwise comparison (keys unique), scatter rank < 300
    for (int i = tid; i < m; i += 1024) {
        unsigned long long ki = sel[i];
        int rank = 0;
        for (int j = 0; j < m; ++j) rank += (sel[j] > ki);
        if (rank < TOPK) top_idx[img * TOPK + rank] = ~((unsigned int)ki);
    }
}

// ---------------- kernel 2.5: wave-per-row decode of the selected 300 ----------------
// row struct (8 floats): x1,y1,x2,y2,score,clsf,unused,unused
__global__ __launch_bounds__(256) void decode_top_kernel(const float* __restrict__ f0,
                                                         const float* __restrict__ f1,
                                                         const float* __restrict__ f2,
                                                         const unsigned int* __restrict__ top_idx,
                                                         float* __restrict__ rows, int nrows) {
    int gw = blockIdx.x * 4 + (threadIdx.x >> 6);
    int lane = threadIdx.x & 63;
    if (gw >= nrows) return;
    int img = gw / TOPK, k = gw - img * TOPK;
    float* row = rows + (size_t)gw * 8;
    unsigned int idx = top_idx[img * TOPK + k];
    if (idx == 0xFFFFFFFFu) {
        if (lane < 8) row[lane] = 0.0f;
        return;
    }
    int level, hw, W, hrow, wcol, a;
    const float* p = locate(f0, f1, f2, img, (int)idx, level, hw, W, hrow, wcol, a);

    // literal per-class sigmoid argmax, wave-parallel, first-max-wins
    float v1 = p[(5 + lane) * hw];
    float bestv = sigf(v1);
    int besti = lane;
    if (lane < 16) {
        float v2 = p[(69 + lane) * hw];
        float sv2 = sigf(v2);
        if (sv2 > bestv) { bestv = sv2; besti = 64 + lane; }   // tie keeps smaller index
    }
    #pragma unroll
    for (int off = 32; off > 0; off >>= 1) {
        float ov = __shfl_xor(bestv, off, 64);
        int oi = __shfl_xor(besti, off, 64);
        if (ov > bestv || (ov == bestv && oi < besti)) { bestv = ov; besti = oi; }
    }

    float tval = (lane < 5) ? p[lane * hw] : 0.0f;
    float tx = __shfl(tval, 0, 64);
    float ty = __shfl(tval, 1, 64);
    float tw = __shfl(tval, 2, 64);
    float th = __shfl(tval, 3, 64);
    float tob = __shfl(tval, 4, 64);

    if (lane == 0) {
        float x = __fdiv_rn(__fadd_rn(sigf(tx), (float)wcol), (float)W);
        float y = __fdiv_rn(__fadd_rn(sigf(ty), (float)hrow), (float)W);   // H == W per level
        float wd = __fdiv_rn(__fmul_rn(expcr(tw), ANCWf[level][a]), 416.0f);
        float ht = __fdiv_rn(__fmul_rn(expcr(th), ANCHf[level][a]), 416.0f);
        float obj = sigf(tob);
        float score = __fmul_rn(obj, bestv);
        if (!(score >= 0.5f)) score = 0.0f;

        float hx = __fmul_rn(wd, 0.5f);
        float hy = __fmul_rn(ht, 0.5f);
        float x1 = __fmul_rn(__fsub_rn(x, hx), 416.0f);
        float y1 = __fmul_rn(__fsub_rn(y, hy), 416.0f);
        float x2 = __fmul_rn(__fadd_rn(x, hx), 416.0f);
        float y2 = __fmul_rn(__fadd_rn(y, hy), 416.0f);

        row[0] = x1; row[1] = y1; row[2] = x2; row[3] = y2;
        row[4] = score; row[5] = (float)besti; row[6] = 0.0f; row[7] = 0.0f;
    }
}

// ---------------- kernel 3: NMS core — ballot bit-matrix + lane-parallel scan ----------------
__global__ __launch_bounds__(1024) void nms_core_kernel(const float* __restrict__ rows,
                                                        float* __restrict__ out) {
    __shared__ float bx0[TOPK], bx1[TOPK], bx2[TOPK], bx3[TOPK];
    __shared__ float bb0[TOPK], bb1[TOPK], bb2[TOPK], bb3[TOPK];
    __shared__ float area[TOPK], sc[TOPK], clsf[TOPK];
    __shared__ unsigned long long sup[TOPK][5];
    __shared__ unsigned long long keepm[5];

    int img = blockIdx.x;
    int tid = threadIdx.x;
    int wave = tid >> 6, lane = tid & 63;

    if (tid < TOPK) {
        const float* row = rows + ((size_t)img * TOPK + tid) * 8;
        float x1 = row[0], y1 = row[1], x2 = row[2], y2 = row[3];
        float score = row[4], cf = row[5];
        float off = __fmul_rn(cf, 832.0f);   // 2*INPUT
        bx0[tid] = x1; bx1[tid] = y1; bx2[tid] = x2; bx3[tid] = y2;
        float b0 = __fadd_rn(x1, off), b1 = __fadd_rn(y1, off);
        float b2 = __fadd_rn(x2, off), b3 = __fadd_rn(y2, off);
        bb0[tid] = b0; bb1[tid] = b1; bb2[tid] = b2; bb3[tid] = b3;
        area[tid] = __fmul_rn(__fsub_rn(b2, b0), __fsub_rn(b3, b1));
        sc[tid] = score;
        clsf[tid] = cf;
    }
    __syncthreads();

    // suppression bit-matrix, wave-parallel; lane's j-box kept in registers per w.
    #pragma unroll
    for (int w = 0; w < 5; ++w) {
        int j = (w << 6) + lane;
        bool jv = (j < TOPK);
        float j0 = jv ? bb0[j] : 0.0f;
        float j1 = jv ? bb1[j] : 0.0f;
        float j2 = jv ? bb2[j] : 0.0f;
        float j3 = jv ? bb3[j] : 0.0f;
        float ja = jv ? area[j] : 0.0f;
        for (int r = wave; r < TOPK; r += 16) {
            // row r reads are wave-uniform -> LDS broadcast (conflict-free)
            float a0 = bb0[r], a1 = bb1[r], a2 = bb2[r], a3 = bb3[r], aa = area[r];
            bool bit = false;
            if (jv && j > r) {
                float ltx = fmaxf(a0, j0);
                float lty = fmaxf(a1, j1);
                float rbx = fminf(a2, j2);
                float rby = fminf(a3, j3);
                float wx = fmaxf(__fsub_rn(rbx, ltx), 0.0f);
                float wy = fmaxf(__fsub_rn(rby, lty), 0.0f);
                float inter = __fmul_rn(wx, wy);
                float denom = __fadd_rn(__fsub_rn(__fadd_rn(aa, ja), inter), 1e-6f);
                float iou = __fdiv_rn(inter, denom);
                bit = (iou > 0.3f);
            }
            unsigned long long m = __ballot(bit);
            if (lane == 0) sup[r][w] = m;
        }
    }
    __syncthreads();

    // lane-parallel greedy scan by wave 0: lane w (w<5) owns keep-word kp.
    if (wave == 0) {
        unsigned long long kp = ~0ULL;
        for (int i = 0; i < TOPK; ++i) {
            unsigned long long kw = __shfl(kp, i >> 6, 64);
            bool keep_i = (kw >> (i & 63)) & 1ULL;
            if (keep_i && lane < 5) kp &= ~sup[i][lane];
        }
        if (lane < 5) keepm[lane] = kp;
    }
    __syncthreads();

    if (tid < TOPK) {
        bool kept = (keepm[tid >> 6] >> (tid & 63)) & 1ULL;
        float m = (kept && (sc[tid] > 0.0f)) ? 1.0f : 0.0f;
        float* o = out + ((size_t)img * TOPK + tid) * 6;
        o[0] = __fmul_rn(bx0[tid], m);
        o[1] = __fmul_rn(bx1[tid], m);
        o[2] = __fmul_rn(bx2[tid], m);
        o[3] = __fmul_rn(bx3[tid], m);
        o[4] = __fmul_rn(sc[tid], m);
        o[5] = __fmul_rn(clsf[tid], m);
    }
}

extern "C" void kernel_launch(void* const* d_in, const int* in_sizes, int n_in,
                              void* d_out, int out_size, void* d_ws, size_t ws_size,
                              hipStream_t stream) {
    const float* f0 = (const float*)d_in[0];
    const float* f1 = (const float*)d_in[1];
    const float* f2 = (const float*)d_in[2];
    float* out = (float*)d_out;

    int B = in_sizes[0] / 43095;   // 255*13*13 (== 32 for this problem)
    int nrows = B * TOPK;

    // workspace: [top_idx B*300 u32][rows B*300*8 f32][keys B*NTOT u64]
    unsigned int* top_idx = (unsigned int*)d_ws;
    size_t off1 = ((size_t)nrows * sizeof(unsigned int) + 255) / 256 * 256;
    float* rows = (float*)((char*)d_ws + off1);
    size_t off2 = off1 + ((size_t)nrows * 8 * sizeof(float) + 255) / 256 * 256;
    unsigned long long* keys = (unsigned long long*)((char*)d_ws + off2);

    // threads: 32*512 (L0) + 32*512 (L1) + 32*2048 (L2) = 98304
    score_kernel<<<98304 / 256, 256, 0, stream>>>(f0, f1, f2, keys);
    topk_kernel<<<B, 1024, 0, stream>>>(keys, top_idx);
    decode_top_kernel<<<(nrows + 3) / 4, 256, 0, stream>>>(f0, f1, f2, top_idx, rows, nrows);
    nms_core_kernel<<<B, 1024, 0, stream>>>(rows, out);
}